// Round 8
// baseline (1986.012 us; speedup 1.0000x reference)
//
#include <hip/hip_runtime.h>

#define NB 1024
#define NV 96
#define WW 128
#define EE 64
#define DD 64

typedef _Float16 h2t __attribute__((ext_vector_type(2)));
typedef float f2t __attribute__((ext_vector_type(2)));
typedef float f4t __attribute__((ext_vector_type(4)));

#define CLOG 2.885390081777927f   /* 2*log2(e) */
#define L2E  1.4426950408889634f  /* log2(e)   */

__device__ __forceinline__ float fdot2(h2t a, h2t b, float c) {
    return __builtin_amdgcn_fdot2(a, b, c, false);
}
__device__ __forceinline__ h2t pk2(float a, float b) {
    h2t r; r.x = (_Float16)a; r.y = (_Float16)b; return r;
}
__device__ __forceinline__ h2t bch(float f) { return __builtin_bit_cast(h2t, f); }
__device__ __forceinline__ float bcf(h2t p) { return __builtin_bit_cast(float, p); }
__device__ __forceinline__ float ex2(float x) { return __builtin_amdgcn_exp2f(x); }
__device__ __forceinline__ float rcp_(float x) { return __builtin_amdgcn_rcpf(x); }
__device__ __forceinline__ float sig_c(float x) { return rcp_(1.f + ex2(-x * L2E)); }
__device__ __forceinline__ float tanh_c(float x) { return 1.f - 2.f * rcp_(ex2(x * CLOG) + 1.f); }
__device__ __forceinline__ float wsum(float v) {
#pragma unroll
    for (int o = 32; o; o >>= 1) v += __shfl_xor(v, o, 64);
    return v;
}

// PWL tanh: idx pre-scaled (idx = 10*arg + 32), 64-entry table in a register
// gathered via ds_bpermute; entry = {tanh(x_i) f16lo, tanh(x_i+0.1)-tanh(x_i) f16hi}.
__device__ __forceinline__ float pwl_t(float idx, int tbl) {
    idx = __builtin_amdgcn_fmed3f(idx, 0.f, 62.999f);
    int i = (int)idx;
    float frac = idx - (float)i;
    int pk = __builtin_amdgcn_ds_bpermute(i << 2, tbl);
    h2t bs = bch(__builtin_bit_cast(float, pk));
    return fmaf((float)bs.y, frac, (float)bs.x);
}

#define DOT4(V, WR, B, ACC) do { \
    ACC = fdot2(bch((V).x), (WR)[(B) + 0], ACC); \
    ACC = fdot2(bch((V).y), (WR)[(B) + 1], ACC); \
    ACC = fdot2(bch((V).z), (WR)[(B) + 2], ACC); \
    ACC = fdot2(bch((V).w), (WR)[(B) + 3], ACC); } while (0)

#define DOT4W(V, W4, ACC) do { \
    ACC = fdot2(bch((V).x), bch((W4).x), ACC); \
    ACC = fdot2(bch((V).y), bch((W4).y), ACC); \
    ACC = fdot2(bch((V).z), bch((W4).z), ACC); \
    ACC = fdot2(bch((V).w), bch((W4).w), ACC); } while (0)

// ======================= 2-elements-per-block kernel =======================
__global__ __launch_bounds__(256, 2)
void darnn2_kernel(
    const float* __restrict__ x,
    const float* __restrict__ eWih, const float* __restrict__ eWhh,
    const float* __restrict__ ebih, const float* __restrict__ ebhh,
    const float* __restrict__ elv,  const float* __restrict__ elw,
    const float* __restrict__ elwb, const float* __restrict__ elu,
    const float* __restrict__ elub,
    const float* __restrict__ dWih, const float* __restrict__ dWhh,
    const float* __restrict__ dbih, const float* __restrict__ dbhh,
    const float* __restrict__ dlv,  const float* __restrict__ dlw,
    const float* __restrict__ dlwb, const float* __restrict__ dlu,
    const float* __restrict__ dlub, const float* __restrict__ dlp,
    const float* __restrict__ dlpb, const float* __restrict__ dly,
    const float* __restrict__ dlyb, const int* __restrict__ tgtp,
    h2t* __restrict__ hsg_all,
    float* __restrict__ out)
{
    // enc: s_pool2[wp*98 + n], wp<64, n<96 | dec: s_pool2[ep*131 + w], ep<32, w<128
    __shared__ __align__(16) f2t  s_pool2[64 * 98];      // 50176 B
    __shared__ __align__(16) f4t  s_wo4[64];             // {woA10, wnA10, woB10, wnB10}
    __shared__ __align__(16) f2t  s_lv[64];
    __shared__ __align__(16) f2t  s_soft2[128];
    __shared__ __align__(16) char s_u2v[2048];
    __shared__ __align__(16) h2t  s_hch2[2][2][64];
    __shared__ __align__(16) f4t  s_spw[4][256];
    __shared__ __align__(16) f4t  s_sph[2][256];
    __shared__ __align__(16) f2t  s_psum[4];
    __shared__ __align__(16) f2t  s_ytp[4];
    __shared__ float s_scal[8];

    h2t*  const s_xtA  = (h2t*)s_u2v;
    h2t*  const s_xtB  = (h2t*)(s_u2v + 1024);

    const int tid  = threadIdx.x;
    const int b    = blockIdx.x;
    const int lane = tid & 63, wq = tid >> 6;
    const int uidx = wq * 16 + (lane >> 2);
    const int jrow = (lane & 3) * 64 + uidx;
    const float* xbA = x + (size_t)(2 * b) * NV * WW;
    const float* xbB = xbA + NV * WW;
    h2t* hsgP = hsg_all + (size_t)b * (WW * 64);   // [w][32 k][2 el]

    float c_regA = 0.f, c_regB = 0.f;

    // ---------------- init ----------------
    if (tid < 64) {
        s_hch2[0][0][tid] = pk2(0.f, 0.f);
        s_hch2[0][1][tid] = pk2(0.f, 0.f);
        f2t lv = { elv[2 * tid], elv[2 * tid + 1] };
        s_lv[tid] = lv;
    }

    // ---------------- PWL tanh table (register, per-lane entry) ----------------
    int tbl;
    {
        float x0 = fmaf((float)lane, 0.1f, -3.2f);
        float t0 = tanh_c(x0);
        float t1 = tanh_c(x0 + 0.1f);
        tbl = __builtin_bit_cast(int, pk2(t0, t1 - t0));
    }

    // ---------------- phase A: u_e (raw fp16, transposed) ----------------
    {
        const int o = tid >> 1, p = tid & 1;
        f4t lu4[16];
        const f4t* lur = (const f4t*)(elu + o * WW + p * 64);
#pragma unroll
        for (int i = 0; i < 16; ++i) lu4[i] = lur[i];
        const float lub_o = elub[o];
        for (int n = 0; n < NV; ++n) {
            const f4t* xrA = (const f4t*)(xbA + n * WW + p * 64);
            const f4t* xrB = (const f4t*)(xbB + n * WW + p * 64);
            float aA0 = 0.f, aA1 = 0.f, aB0 = 0.f, aB1 = 0.f;
#pragma unroll
            for (int i = 0; i < 8; ++i) {
                f4t vA = xrA[i], vB = xrB[i], l4 = lu4[i];
                f4t wA = xrA[8 + i], wB = xrB[8 + i], m4 = lu4[8 + i];
                aA0 = fmaf(vA.x, l4.x, aA0); aA0 = fmaf(vA.y, l4.y, aA0);
                aA0 = fmaf(vA.z, l4.z, aA0); aA0 = fmaf(vA.w, l4.w, aA0);
                aA1 = fmaf(wA.x, m4.x, aA1); aA1 = fmaf(wA.y, m4.y, aA1);
                aA1 = fmaf(wA.z, m4.z, aA1); aA1 = fmaf(wA.w, m4.w, aA1);
                aB0 = fmaf(vB.x, l4.x, aB0); aB0 = fmaf(vB.y, l4.y, aB0);
                aB0 = fmaf(vB.z, l4.z, aB0); aB0 = fmaf(vB.w, l4.w, aB0);
                aB1 = fmaf(wB.x, m4.x, aB1); aB1 = fmaf(wB.y, m4.y, aB1);
                aB1 = fmaf(wB.z, m4.z, aB1); aB1 = fmaf(wB.w, m4.w, aB1);
            }
            float aA = aA0 + aA1, aB = aB0 + aB1;
            aA += __shfl_xor(aA, 1, 64);
            aB += __shfl_xor(aB, 1, 64);
            float valA = aA + lub_o;
            float valB = aB + lub_o;
            float vnA = __shfl_xor(valA, 2, 64);
            float vnB = __shfl_xor(valB, 2, 64);
            if (!(tid & 3)) {
                const int op = tid >> 2;
                f2t st = { bcf(pk2(valA, vnA)), bcf(pk2(valB, vnB)) };
                s_pool2[op * 98 + n] = st;
            }
        }
    }
    __syncthreads();
    __builtin_amdgcn_sched_barrier(0);

    // ---------------- encoder weights ----------------
    h2t lw_r[32];
    {
        const f2t* r = (const f2t*)(elw + (tid >> 1) * 128 + (tid & 1) * 64);
#pragma unroll
        for (int i = 0; i < 32; ++i) { f2t v = r[i]; lw_r[i] = pk2(v.x, v.y); }
    }
    const float lwb10_r = fmaf(elwb[tid >> 1], 10.f, 32.f);
    h2t wih_r[32];
    {
        const f2t* r = (const f2t*)(eWih + jrow * 96);
#pragma unroll
        for (int i = 0; i < 32; ++i) { f2t v = r[i]; wih_r[i] = pk2(v.x, v.y); }
#pragma unroll
        for (int g = 0; g < 4; ++g) {
            f4t ws;
            { f2t v = r[32 + 4*g];     ws.x = bcf(pk2(v.x, v.y)); }
            { f2t v = r[33 + 4*g];     ws.y = bcf(pk2(v.x, v.y)); }
            { f2t v = r[34 + 4*g];     ws.z = bcf(pk2(v.x, v.y)); }
            { f2t v = r[35 + 4*g];     ws.w = bcf(pk2(v.x, v.y)); }
            s_spw[g][tid] = ws;
        }
    }
    h2t whh_r[24];
    {
        const f2t* r = (const f2t*)(eWhh + jrow * 64);
#pragma unroll
        for (int i = 0; i < 24; ++i) { f2t v = r[i]; whh_r[i] = pk2(v.x, v.y); }
#pragma unroll
        for (int g = 0; g < 2; ++g) {
            f4t ws;
            { f2t v = r[24 + 4*g];     ws.x = bcf(pk2(v.x, v.y)); }
            { f2t v = r[25 + 4*g];     ws.y = bcf(pk2(v.x, v.y)); }
            { f2t v = r[26 + 4*g];     ws.z = bcf(pk2(v.x, v.y)); }
            { f2t v = r[27 + 4*g];     ws.w = bcf(pk2(v.x, v.y)); }
            s_sph[g][tid] = ws;
        }
    }
    const float bsum_r = ebih[jrow] + ebhh[jrow];
    __builtin_amdgcn_sched_barrier(0);

    // ---------------- encoder recurrence: 3 barriers/step ----------------
#pragma unroll 1
    for (int t = 0; t < WW; ++t) {
        const int pp = t & 1;
        float xvA = 0.f, xvB = 0.f;
        if (!(tid & 1) && tid < 192) {
            const int n = tid >> 1;
            xvA = xbA[n * WW + t]; xvB = xbB[n * WW + t];
        }
        // ph1: w_out both elements (pre-scaled for PWL index)
        {
            const f4t* hcA = (const f4t*)&s_hch2[pp][0][(tid & 1) * 32];
            const f4t* hcB = (const f4t*)&s_hch2[pp][1][(tid & 1) * 32];
            float aA0 = 0.f, aA1 = 0.f, aB0 = 0.f, aB1 = 0.f;
#pragma unroll
            for (int i = 0; i < 4; ++i) {
                f4t vA = hcA[i], vB = hcB[i];
                f4t wA = hcA[4 + i], wB = hcB[4 + i];
                DOT4(vA, lw_r, 4 * i, aA0);
                DOT4(wA, lw_r, 16 + 4 * i, aA1);
                DOT4(vB, lw_r, 4 * i, aB0);
                DOT4(wB, lw_r, 16 + 4 * i, aB1);
            }
            float aA = aA0 + aA1, aB = aB0 + aB1;
            aA += __shfl_xor(aA, 1, 64); aB += __shfl_xor(aB, 1, 64);
            float woA = fmaf(aA, 10.f, lwb10_r), woB = fmaf(aB, 10.f, lwb10_r);
            float wnA = __shfl_xor(woA, 2, 64), wnB = __shfl_xor(woB, 2, 64);
            if (!(tid & 3)) { f4t st = {woA, wnA, woB, wnB}; s_wo4[tid >> 2] = st; }
        }
        __syncthreads();
        // ph2: scores via PWL-tanh + exp, unnormalized x_tilde, per-wave psum
        float prodA = 0.f, prodB = 0.f, eA = 0.f, eB = 0.f;
        if (tid < 192) {
            const int n = tid >> 1, part = tid & 1;
            const f4t* wor = s_wo4 + part * 32;
            const f2t* lvr = s_lv + part * 32;
            const f2t* uer = s_pool2 + part * 32 * 98 + n;
            float aA0 = 0.f, aA1 = 0.f, aB0 = 0.f, aB1 = 0.f;
#pragma unroll
            for (int j = 0; j < 16; ++j) {
                {
                    f4t w4 = wor[j];
                    f2t lv = lvr[j];
                    f2t up = uer[j * 98];
                    h2t uA = bch(up.x), uB = bch(up.y);
                    aA0 = fmaf(lv.x, pwl_t(fmaf((float)uA.x, 10.f, w4.x), tbl), aA0);
                    aA0 = fmaf(lv.y, pwl_t(fmaf((float)uA.y, 10.f, w4.y), tbl), aA0);
                    aB0 = fmaf(lv.x, pwl_t(fmaf((float)uB.x, 10.f, w4.z), tbl), aB0);
                    aB0 = fmaf(lv.y, pwl_t(fmaf((float)uB.y, 10.f, w4.w), tbl), aB0);
                }
                {
                    f4t w4 = wor[16 + j];
                    f2t lv = lvr[16 + j];
                    f2t up = uer[(16 + j) * 98];
                    h2t uA = bch(up.x), uB = bch(up.y);
                    aA1 = fmaf(lv.x, pwl_t(fmaf((float)uA.x, 10.f, w4.x), tbl), aA1);
                    aA1 = fmaf(lv.y, pwl_t(fmaf((float)uA.y, 10.f, w4.y), tbl), aA1);
                    aB1 = fmaf(lv.x, pwl_t(fmaf((float)uB.x, 10.f, w4.z), tbl), aB1);
                    aB1 = fmaf(lv.y, pwl_t(fmaf((float)uB.y, 10.f, w4.w), tbl), aB1);
                }
            }
            float aA = aA0 + aA1, aB = aB0 + aB1;
            aA += __shfl_xor(aA, 1, 64); aB += __shfl_xor(aB, 1, 64);
            if (!(tid & 1)) {
                eA = ex2(aA * L2E);
                eB = ex2(aB * L2E);
                prodA = eA * xvA; prodB = eB * xvB;
            }
        }
        {
            float p1A = __shfl_xor(prodA, 2, 64), p1B = __shfl_xor(prodB, 2, 64);
            if (tid < 192 && !(tid & 3)) {
                s_xtA[tid >> 2] = pk2(prodA, p1A);
                s_xtB[tid >> 2] = pk2(prodB, p1B);
            }
        }
        {
            float sA = eA, sB = eB;
#pragma unroll
            for (int o = 32; o; o >>= 1) { sA += __shfl_xor(sA, o, 64); sB += __shfl_xor(sB, o, 64); }
            if (lane == 0) { f2t st = {sA, sB}; s_psum[wq] = st; }
        }
        __syncthreads();
        // ph4: gates + fused LSTM update
        {
            f2t q0 = s_psum[0], q1 = s_psum[1], q2 = s_psum[2], q3 = s_psum[3];
            const float invA = rcp_((q0.x + q1.x) + (q2.x + q3.x));
            const float invB = rcp_((q0.y + q1.y) + (q2.y + q3.y));
            float gxA0 = 0.f, gxA1 = 0.f, gxB0 = 0.f, gxB1 = 0.f;
            float ghA0 = bsum_r, ghA1 = 0.f, ghB0 = bsum_r, ghB1 = 0.f;
            const f4t* xtA4 = (const f4t*)s_xtA;
            const f4t* xtB4 = (const f4t*)s_xtB;
#pragma unroll
            for (int i = 0; i < 4; ++i) {
                f4t vA = xtA4[i], vB = xtB4[i];
                f4t wA = xtA4[4 + i], wB = xtB4[4 + i];
                DOT4(vA, wih_r, 4 * i, gxA0);
                DOT4(wA, wih_r, 16 + 4 * i, gxA1);
                DOT4(vB, wih_r, 4 * i, gxB0);
                DOT4(wB, wih_r, 16 + 4 * i, gxB1);
            }
#pragma unroll
            for (int g = 0; g < 2; ++g) {
                f4t w0 = s_spw[g][tid], w1 = s_spw[2 + g][tid];
                f4t vA = xtA4[8 + g], vB = xtB4[8 + g];
                f4t wA = xtA4[10 + g], wB = xtB4[10 + g];
                DOT4W(vA, w0, gxA0); DOT4W(wA, w1, gxA1);
                DOT4W(vB, w0, gxB0); DOT4W(wB, w1, gxB1);
            }
            const f4t* hA4 = (const f4t*)&s_hch2[pp][0][0];
            const f4t* hB4 = (const f4t*)&s_hch2[pp][1][0];
#pragma unroll
            for (int i = 0; i < 3; ++i) {
                f4t vA = hA4[i], vB = hB4[i];
                f4t wA = hA4[3 + i], wB = hB4[3 + i];
                DOT4(vA, whh_r, 4 * i, ghA0);
                DOT4(wA, whh_r, 12 + 4 * i, ghA1);
                DOT4(vB, whh_r, 4 * i, ghB0);
                DOT4(wB, whh_r, 12 + 4 * i, ghB1);
            }
            {
                f4t w0 = s_sph[0][tid], w1 = s_sph[1][tid];
                f4t vA = hA4[6], wA = hA4[7];
                f4t vB = hB4[6], wB = hB4[7];
                DOT4W(vA, w0, ghA0); DOT4W(wA, w1, ghA1);
                DOT4W(vB, w0, ghB0); DOT4W(wB, w1, ghB1);
            }
            float gA = fmaf(gxA0 + gxA1, invA, ghA0 + ghA1);
            float gB = fmaf(gxB0 + gxB1, invB, ghB0 + ghB1);
            const int base = lane & ~3;
            float giA = __shfl(gA, base, 64),     giB = __shfl(gB, base, 64);
            float gfA = __shfl(gA, base + 1, 64), gfB = __shfl(gB, base + 1, 64);
            float g2A = __shfl(gA, base + 2, 64), g2B = __shfl(gB, base + 2, 64);
            float goA = __shfl(gA, base + 3, 64), goB = __shfl(gB, base + 3, 64);
            float cA = sig_c(gfA) * c_regA + sig_c(giA) * tanh_c(g2A);
            float cB = sig_c(gfB) * c_regB + sig_c(giB) * tanh_c(g2B);
            float hA = sig_c(goA) * tanh_c(cA);
            float hB = sig_c(goB) * tanh_c(cB);
            c_regA = cA; c_regB = cB;
            float hnA = __shfl_xor(hA, 4, 64), cnA = __shfl_xor(cA, 4, 64);
            float hnB = __shfl_xor(hB, 4, 64), cnB = __shfl_xor(cB, 4, 64);
            if (!(lane & 7)) {
                const int k = wq * 8 + (lane >> 3);
                h2t phA = pk2(hA, hnA), phB = pk2(hB, hnB);
                s_hch2[pp ^ 1][0][k]      = phA;
                s_hch2[pp ^ 1][0][32 + k] = pk2(cA, cnA);
                s_hch2[pp ^ 1][1][k]      = phB;
                s_hch2[pp ^ 1][1][32 + k] = pk2(cB, cnB);
                f2t st = { bcf(phA), bcf(phB) };
                *(f2t*)&hsgP[t * 64 + k * 2] = st;
            }
        }
        __syncthreads();
    }

    // ---------------- u_d = h_seq @ dlu^T + dlub (raw, transposed, stride 131) ----
    {
        const int e2h = tid & 31;
        h2t du0[32], du1[32];
        {
            const f4t* p0 = (const f4t*)(dlu + (2 * e2h) * 64);
            const f4t* p1 = (const f4t*)(dlu + (2 * e2h + 1) * 64);
#pragma unroll
            for (int i = 0; i < 16; ++i) {
                f4t v0 = p0[i], v1 = p1[i];
                du0[2 * i] = pk2(v0.x, v0.y); du0[2 * i + 1] = pk2(v0.z, v0.w);
                du1[2 * i] = pk2(v1.x, v1.y); du1[2 * i + 1] = pk2(v1.z, v1.w);
            }
        }
        const float b0 = dlub[2 * e2h], b1 = dlub[2 * e2h + 1];
#pragma unroll 1
        for (int pass = 0; pass < 16; ++pass) {
            const int w = pass * 8 + (tid >> 5);
            float a0A = b0, a1A = b1, a0B = b0, a1B = b1;
            const f4t* hr = (const f4t*)(hsgP + w * 64);
#pragma unroll
            for (int i = 0; i < 16; ++i) {
                f4t v = hr[i];
                a0A = fdot2(bch(v.x), du0[2*i], a0A); a0A = fdot2(bch(v.z), du0[2*i+1], a0A);
                a1A = fdot2(bch(v.x), du1[2*i], a1A); a1A = fdot2(bch(v.z), du1[2*i+1], a1A);
                a0B = fdot2(bch(v.y), du0[2*i], a0B); a0B = fdot2(bch(v.w), du0[2*i+1], a0B);
                a1B = fdot2(bch(v.y), du1[2*i], a1B); a1B = fdot2(bch(v.w), du1[2*i+1], a1B);
            }
            f2t st = { bcf(pk2(a0A, a1A)), bcf(pk2(a0B, a1B)) };
            s_pool2[e2h * 131 + w] = st;
        }
    }
    __builtin_amdgcn_sched_barrier(0);

    // ---------------- decoder setup ----------------
    const int tgt = tgtp[0];
    if (tid < 32) { f2t lv = { dlv[2 * tid], dlv[2 * tid + 1] }; s_lv[tid] = lv; }
    if (tid < 64) {
        s_hch2[0][0][tid] = pk2(0.f, 0.f);
        s_hch2[0][1][tid] = pk2(0.f, 0.f);
    }
    h2t dlw_r[16];
    {
        const f2t* r = (const f2t*)(dlw + (tid >> 2) * 128 + (tid & 3) * 32);
#pragma unroll
        for (int i = 0; i < 16; ++i) { f2t v = r[i]; dlw_r[i] = pk2(v.x, v.y); }
    }
    const float dlwb10_r = fmaf(dlwb[tid >> 2], 10.f, 32.f);
    h2t dwhh_r[24];
    {
        const f2t* r = (const f2t*)(dWhh + jrow * 64);
#pragma unroll
        for (int i = 0; i < 24; ++i) { f2t v = r[i]; dwhh_r[i] = pk2(v.x, v.y); }
#pragma unroll
        for (int g = 0; g < 2; ++g) {
            f4t ws;
            { f2t v = r[24 + 4*g]; ws.x = bcf(pk2(v.x, v.y)); }
            { f2t v = r[25 + 4*g]; ws.y = bcf(pk2(v.x, v.y)); }
            { f2t v = r[26 + 4*g]; ws.z = bcf(pk2(v.x, v.y)); }
            { f2t v = r[27 + 4*g]; ws.w = bcf(pk2(v.x, v.y)); }
            s_sph[g][tid] = ws;
        }
    }
    const float dwih_r  = dWih[jrow];
    const float dbsum_r = dbih[jrow] + dbhh[jrow];
    const float lp0     = dlp[0];
    const h2t   lp1p    = pk2(dlp[1 + 2 * (tid & 31)], dlp[2 + 2 * (tid & 31)]);
    const float lpb     = dlpb[0];
    c_regA = 0.f; c_regB = 0.f;
    float h_regA = 0.f, h_regB = 0.f;
    __syncthreads();

    // ---------------- decoder recurrence ----------------
#pragma unroll 1
    for (int s = 0; s < WW - 1; ++s) {
        const int pp = s & 1;
        const float ysA = xbA[(size_t)tgt * WW + s];
        const float ysB = xbB[(size_t)tgt * WW + s];
        // ph1': w_out_d (pre-scaled)
        {
            const f4t* hcA = (const f4t*)&s_hch2[pp][0][(tid & 3) * 16];
            const f4t* hcB = (const f4t*)&s_hch2[pp][1][(tid & 3) * 16];
            float aA0 = 0.f, aA1 = 0.f, aB0 = 0.f, aB1 = 0.f;
#pragma unroll
            for (int i = 0; i < 2; ++i) {
                f4t vA = hcA[i], vB = hcB[i];
                f4t wA = hcA[2 + i], wB = hcB[2 + i];
                DOT4(vA, dlw_r, 4 * i, aA0);
                DOT4(wA, dlw_r, 8 + 4 * i, aA1);
                DOT4(vB, dlw_r, 4 * i, aB0);
                DOT4(wB, dlw_r, 8 + 4 * i, aB1);
            }
            float aA = aA0 + aA1, aB = aB0 + aB1;
            aA += __shfl_xor(aA, 1, 64); aB += __shfl_xor(aB, 1, 64);
            aA += __shfl_xor(aA, 2, 64); aB += __shfl_xor(aB, 2, 64);
            float woA = fmaf(aA, 10.f, dlwb10_r), woB = fmaf(aB, 10.f, dlwb10_r);
            float wnA = __shfl_xor(woA, 4, 64), wnB = __shfl_xor(woB, 4, 64);
            if (!(tid & 7)) { f4t st = {woA, wnA, woB, wnB}; s_wo4[tid >> 3] = st; }
        }
        __syncthreads();
        // ph2': v scores via PWL-tanh + exp + per-wave psum
        {
            const int w = tid >> 1, part = tid & 1;
            const f4t* wor = s_wo4 + part * 16;
            const f2t* lvr = s_lv + part * 16;
            const f2t* udr = s_pool2 + w;
            const int rbase = part * 16;
            float aA0 = 0.f, aA1 = 0.f, aB0 = 0.f, aB1 = 0.f;
#pragma unroll
            for (int j = 0; j < 8; ++j) {
                {
                    f4t w4 = wor[j];
                    f2t lv = lvr[j];
                    f2t up = udr[(rbase + j) * 131];
                    h2t uA = bch(up.x), uB = bch(up.y);
                    aA0 = fmaf(lv.x, pwl_t(fmaf((float)uA.x, 10.f, w4.x), tbl), aA0);
                    aA0 = fmaf(lv.y, pwl_t(fmaf((float)uA.y, 10.f, w4.y), tbl), aA0);
                    aB0 = fmaf(lv.x, pwl_t(fmaf((float)uB.x, 10.f, w4.z), tbl), aB0);
                    aB0 = fmaf(lv.y, pwl_t(fmaf((float)uB.y, 10.f, w4.w), tbl), aB0);
                }
                {
                    f4t w4 = wor[8 + j];
                    f2t lv = lvr[8 + j];
                    f2t up = udr[(rbase + 8 + j) * 131];
                    h2t uA = bch(up.x), uB = bch(up.y);
                    aA1 = fmaf(lv.x, pwl_t(fmaf((float)uA.x, 10.f, w4.x), tbl), aA1);
                    aA1 = fmaf(lv.y, pwl_t(fmaf((float)uA.y, 10.f, w4.y), tbl), aA1);
                    aB1 = fmaf(lv.x, pwl_t(fmaf((float)uB.x, 10.f, w4.z), tbl), aB1);
                    aB1 = fmaf(lv.y, pwl_t(fmaf((float)uB.y, 10.f, w4.w), tbl), aB1);
                }
            }
            float aA = aA0 + aA1, aB = aB0 + aB1;
            aA += __shfl_xor(aA, 1, 64); aB += __shfl_xor(aB, 1, 64);
            float eA = 0.f, eB = 0.f;
            if (!(tid & 1)) {
                eA = ex2(aA * L2E);
                eB = ex2(aB * L2E);
                f2t st = {eA, eB}; s_soft2[w] = st;
            }
            float sA = eA, sB = eB;
#pragma unroll
            for (int o = 32; o; o >>= 1) { sA += __shfl_xor(sA, o, 64); sB += __shfl_xor(sB, o, 64); }
            if (lane == 0) { f2t st = {sA, sB}; s_psum[wq] = st; }
        }
        __syncthreads();
        // ph3': fused context -> y_tilde partials
        {
            const int e2 = tid & 31, pg = tid >> 5;
            float ytA0 = 0.f, ytA1 = 0.f, ytB0 = 0.f, ytB1 = 0.f;
#pragma unroll
            for (int j = 0; j < 8; ++j) {
                const int w0 = pg * 16 + j, w1 = pg * 16 + 8 + j;
                f2t be0 = s_soft2[w0], be1 = s_soft2[w1];
                f2t hp0 = *(const f2t*)&hsgP[w0 * 64 + e2 * 2];
                f2t hp1 = *(const f2t*)&hsgP[w1 * 64 + e2 * 2];
                ytA0 = fmaf(be0.x, fdot2(bch(hp0.x), lp1p, 0.f), ytA0);
                ytA1 = fmaf(be1.x, fdot2(bch(hp1.x), lp1p, 0.f), ytA1);
                ytB0 = fmaf(be0.y, fdot2(bch(hp0.y), lp1p, 0.f), ytB0);
                ytB1 = fmaf(be1.y, fdot2(bch(hp1.y), lp1p, 0.f), ytB1);
            }
            float ytA = ytA0 + ytA1, ytB = ytB0 + ytB1;
#pragma unroll
            for (int o = 32; o; o >>= 1) { ytA += __shfl_xor(ytA, o, 64); ytB += __shfl_xor(ytB, o, 64); }
            if (lane == 0) { f2t st = {ytA, ytB}; s_ytp[wq] = st; }
        }
        __syncthreads();
        // ph4': y_tilde + gates + update
        {
            f2t q0 = s_psum[0], q1 = s_psum[1], q2 = s_psum[2], q3 = s_psum[3];
            f2t y0 = s_ytp[0],  y1 = s_ytp[1],  y2 = s_ytp[2],  y3 = s_ytp[3];
            const float invA = rcp_((q0.x + q1.x) + (q2.x + q3.x));
            const float invB = rcp_((q0.y + q1.y) + (q2.y + q3.y));
            float ytA = fmaf(ysA, lp0, ((y0.x + y1.x) + (y2.x + y3.x)) * invA + lpb);
            float ytB = fmaf(ysB, lp0, ((y0.y + y1.y) + (y2.y + y3.y)) * invB + lpb);
            float gA0 = fmaf(ytA, dwih_r, dbsum_r), gA1 = 0.f;
            float gB0 = fmaf(ytB, dwih_r, dbsum_r), gB1 = 0.f;
            const f4t* hA4 = (const f4t*)&s_hch2[pp][0][0];
            const f4t* hB4 = (const f4t*)&s_hch2[pp][1][0];
#pragma unroll
            for (int i = 0; i < 3; ++i) {
                f4t vA = hA4[i], vB = hB4[i];
                f4t wA = hA4[3 + i], wB = hB4[3 + i];
                DOT4(vA, dwhh_r, 4 * i, gA0);
                DOT4(wA, dwhh_r, 12 + 4 * i, gA1);
                DOT4(vB, dwhh_r, 4 * i, gB0);
                DOT4(wB, dwhh_r, 12 + 4 * i, gB1);
            }
            {
                f4t w0 = s_sph[0][tid], w1 = s_sph[1][tid];
                f4t vA = hA4[6], wA = hA4[7];
                f4t vB = hB4[6], wB = hB4[7];
                DOT4W(vA, w0, gA0); DOT4W(wA, w1, gA1);
                DOT4W(vB, w0, gB0); DOT4W(wB, w1, gB1);
            }
            float gA = gA0 + gA1, gB = gB0 + gB1;
            const int base = lane & ~3;
            float giA = __shfl(gA, base, 64),     giB = __shfl(gB, base, 64);
            float gfA = __shfl(gA, base + 1, 64), gfB = __shfl(gB, base + 1, 64);
            float g2A = __shfl(gA, base + 2, 64), g2B = __shfl(gB, base + 2, 64);
            float goA = __shfl(gA, base + 3, 64), goB = __shfl(gB, base + 3, 64);
            float cA = sig_c(gfA) * c_regA + sig_c(giA) * tanh_c(g2A);
            float cB = sig_c(gfB) * c_regB + sig_c(giB) * tanh_c(g2B);
            float hA = sig_c(goA) * tanh_c(cA);
            float hB = sig_c(goB) * tanh_c(cB);
            c_regA = cA; c_regB = cB; h_regA = hA; h_regB = hB;
            float hnA = __shfl_xor(hA, 4, 64), cnA = __shfl_xor(cA, 4, 64);
            float hnB = __shfl_xor(hB, 4, 64), cnB = __shfl_xor(cB, 4, 64);
            if (!(lane & 7)) {
                const int k = wq * 8 + (lane >> 3);
                s_hch2[pp ^ 1][0][k]      = pk2(hA, hnA);
                s_hch2[pp ^ 1][0][32 + k] = pk2(cA, cnA);
                s_hch2[pp ^ 1][1][k]      = pk2(hB, hnB);
                s_hch2[pp ^ 1][1][32 + k] = pk2(cB, cnB);
            }
        }
        __syncthreads();
    }

    // ---------------- output ----------------
    {
        float termA = 0.f, termB = 0.f;
        if (!(lane & 3)) {
            termA = h_regA * dly[uidx] + c_regA * dly[64 + uidx];
            termB = h_regB * dly[uidx] + c_regB * dly[64 + uidx];
        }
#pragma unroll
        for (int o = 32; o; o >>= 1) {
            termA += __shfl_xor(termA, o, 64);
            termB += __shfl_xor(termB, o, 64);
        }
        if (lane == 0) { s_scal[wq] = termA; s_scal[4 + wq] = termB; }
    }
    __syncthreads();
    if (tid == 0) out[2 * b]     = s_scal[0] + s_scal[1] + s_scal[2] + s_scal[3] + dlyb[0];
    if (tid == 1) out[2 * b + 1] = s_scal[4] + s_scal[5] + s_scal[6] + s_scal[7] + dlyb[0];
}

// ======================= fallback: 1-element kernel (LDS h_seq) ========
__global__ __launch_bounds__(256, 2)
void darnn1_kernel(
    const float* __restrict__ x,
    const float* __restrict__ eWih, const float* __restrict__ eWhh,
    const float* __restrict__ ebih, const float* __restrict__ ebhh,
    const float* __restrict__ elv,  const float* __restrict__ elw,
    const float* __restrict__ elwb, const float* __restrict__ elu,
    const float* __restrict__ elub,
    const float* __restrict__ dWih, const float* __restrict__ dWhh,
    const float* __restrict__ dbih, const float* __restrict__ dbhh,
    const float* __restrict__ dlv,  const float* __restrict__ dlw,
    const float* __restrict__ dlwb, const float* __restrict__ dlu,
    const float* __restrict__ dlub, const float* __restrict__ dlp,
    const float* __restrict__ dlpb, const float* __restrict__ dly,
    const float* __restrict__ dlyb, const int* __restrict__ tgtp,
    float* __restrict__ out)
{
    __shared__ __align__(16) h2t  s_pool[96 * 64];
    __shared__ __align__(16) h2t  s_hseq2[WW][32];
    __shared__ __align__(16) f4t  s_wlv[64];
    __shared__ __align__(16) char s_u2[1024];
    __shared__ __align__(16) float s_soft[128];
    __shared__ __align__(16) h2t  s_hch2[2][64];
    __shared__ __align__(16) f4t  s_spillh[2][256];
    __shared__ __align__(16) f4t  s_spillw[256];

    float* s_wlvf = (float*)s_wlv;
    h2t*  const s_xt  = (h2t*)s_u2;
    float* const s_tmp = (float*)s_u2;

    const int tid  = threadIdx.x;
    const int b    = blockIdx.x;
    const int lane = tid & 63, wq = tid >> 6;
    const int uidx = wq * 16 + (lane >> 2);
    const int jrow = (lane & 3) * 64 + uidx;
    const float* xb = x + (size_t)b * NV * WW;

    float c_reg = 0.f;

    if (tid >= 96 && tid < 128) s_soft[tid] = 0.f;
    if (tid < 64) {
        s_hch2[0][tid] = pk2(0.f, 0.f);
        s_wlvf[tid * 4 + 2] = elv[2 * tid];
        s_wlvf[tid * 4 + 3] = elv[2 * tid + 1];
    }
    {
        const int o = tid >> 1, p = tid & 1;
        f4t lu4[16];
        const f4t* lur = (const f4t*)(elu + o * WW + p * 64);
#pragma unroll
        for (int i = 0; i < 16; ++i) lu4[i] = lur[i];
        const float lub_o = elub[o];
        for (int n = 0; n < NV; ++n) {
            const f4t* xr = (const f4t*)(xb + n * WW + p * 64);
            float a = 0.f;
#pragma unroll
            for (int i = 0; i < 16; ++i) {
                f4t v = xr[i], l4 = lu4[i];
                a = fmaf(v.x, l4.x, a); a = fmaf(v.y, l4.y, a);
                a = fmaf(v.z, l4.z, a); a = fmaf(v.w, l4.w, a);
            }
            a += __shfl_xor(a, 1, 64);
            float val = (a + lub_o) * CLOG;
            float vn  = __shfl_xor(val, 2, 64);
            if (!(tid & 3)) s_pool[n * 64 + ((tid >> 2) ^ (n & 31))] = pk2(val, vn);
        }
    }
    __syncthreads();
    __builtin_amdgcn_sched_barrier(0);

    float elvsum;
    {
        const f2t lvp = *(const f2t*)&s_wlvf[(tid & 63) * 4 + 2];
        elvsum = wsum(lvp.x + lvp.y);
    }
    h2t lw_r[32];
    {
        const f2t* r = (const f2t*)(elw + (tid >> 1) * 128 + (tid & 1) * 64);
#pragma unroll
        for (int i = 0; i < 32; ++i) { f2t v = r[i]; lw_r[i] = pk2(v.x, v.y); }
    }
    const float lwb_r = elwb[tid >> 1];
    h2t wih_r[44];
    {
        const f2t* r = (const f2t*)(eWih + jrow * 96);
#pragma unroll
        for (int i = 0; i < 44; ++i) { f2t v = r[i]; wih_r[i] = pk2(v.x, v.y); }
        f4t ws;
        { f2t v = r[44]; ws.x = bcf(pk2(v.x, v.y)); }
        { f2t v = r[45]; ws.y = bcf(pk2(v.x, v.y)); }
        { f2t v = r[46]; ws.z = bcf(pk2(v.x, v.y)); }
        { f2t v = r[47]; ws.w = bcf(pk2(v.x, v.y)); }
        s_spillw[tid] = ws;
    }
    h2t whh_r[24];
    {
        const f2t* r = (const f2t*)(eWhh + jrow * 64);
#pragma unroll
        for (int i = 0; i < 24; ++i) { f2t v = r[i]; whh_r[i] = pk2(v.x, v.y); }
        f4t w0, w1;
        { f2t v = r[24]; w0.x = bcf(pk2(v.x, v.y)); }
        { f2t v = r[25]; w0.y = bcf(pk2(v.x, v.y)); }
        { f2t v = r[26]; w0.z = bcf(pk2(v.x, v.y)); }
        { f2t v = r[27]; w0.w = bcf(pk2(v.x, v.y)); }
        { f2t v = r[28]; w1.x = bcf(pk2(v.x, v.y)); }
        { f2t v = r[29]; w1.y = bcf(pk2(v.x, v.y)); }
        { f2t v = r[30]; w1.z = bcf(pk2(v.x, v.y)); }
        { f2t v = r[31]; w1.w = bcf(pk2(v.x, v.y)); }
        s_spillh[0][tid] = w0;
        s_spillh[1][tid] = w1;
    }
    const float bsum_r = ebih[jrow] + ebhh[jrow];
    __builtin_amdgcn_sched_barrier(0);

#pragma unroll 1
    for (int t = 0; t < WW; ++t) {
        const int pp = t & 1;
        float xv = 0.f;
        if (!(tid & 1) && tid < 192) xv = xb[(tid >> 1) * WW + t];
        {
            const f4t* hc4 = (const f4t*)&s_hch2[pp][(tid & 1) * 32];
            float a = 0.f;
#pragma unroll
            for (int i = 0; i < 8; ++i) { f4t v = hc4[i]; DOT4(v, lw_r, 4 * i, a); }
            a += __shfl_xor(a, 1, 64);
            float wo = (a + lwb_r) * CLOG;
            float wn = __shfl_xor(wo, 2, 64);
            if (!(tid & 3)) { f2t st = {wo, wn}; *(f2t*)&s_wlvf[(tid >> 2) * 4] = st; }
        }
        __syncthreads();
        float prod = 0.f;
        if (tid < 192) {
            const int n = tid >> 1, sw = n & 31;
            const h2t* uer = s_pool + n * 64;
            float a = 0.f;
#pragma unroll
            for (int j = 0; j < 32; ++j) {
                const int wp = (tid & 1) * 32 + j;
                f4t wl = s_wlv[wp];
                h2t u  = uer[wp ^ sw];
                float r0 = rcp_(ex2(wl.x + (float)u.x) + 1.f);
                float r1 = rcp_(ex2(wl.y + (float)u.y) + 1.f);
                a = fmaf(wl.z, r0, a);
                a = fmaf(wl.w, r1, a);
            }
            a += __shfl_xor(a, 1, 64);
            if (!(tid & 1)) {
                float e = ex2((elvsum - 2.f * a) * L2E);
                prod = e * xv;
                s_soft[tid >> 1] = e;
            }
        }
        __syncthreads();
        if (tid < 192) {
            const int l = tid & 63;
            float sm = s_soft[l] + s_soft[64 + l];
            sm = wsum(sm);
            float inv = rcp_(sm);
            float p1 = __shfl_xor(prod, 2, 64);
            if (!(tid & 3)) s_xt[tid >> 2] = pk2(prod * inv, p1 * inv);
        }
        __syncthreads();
        {
            float gv = bsum_r;
            const f4t* xt4 = (const f4t*)s_xt;
#pragma unroll
            for (int i = 0; i < 11; ++i) { f4t v = xt4[i]; DOT4(v, wih_r, 4 * i, gv); }
            { f4t v = xt4[11]; f4t w = s_spillw[tid]; DOT4W(v, w, gv); }
            const f4t* h4 = (const f4t*)&s_hch2[pp][0];
#pragma unroll
            for (int i = 0; i < 6; ++i) { f4t v = h4[i]; DOT4(v, whh_r, 4 * i, gv); }
            { f4t v = h4[6]; f4t w = s_spillh[0][tid]; DOT4W(v, w, gv); }
            { f4t v = h4[7]; f4t w = s_spillh[1][tid]; DOT4W(v, w, gv); }
            const int base = lane & ~3;
            float gi = __shfl(gv, base, 64);
            float gf = __shfl(gv, base + 1, 64);
            float g2 = __shfl(gv, base + 2, 64);
            float go = __shfl(gv, base + 3, 64);
            float c = sig_c(gf) * c_reg + sig_c(gi) * tanh_c(g2);
            float h = sig_c(go) * tanh_c(c);
            c_reg = c;
            float hn = __shfl_xor(h, 4, 64);
            float cn = __shfl_xor(c, 4, 64);
            if (!(lane & 7)) {
                const int k = wq * 8 + (lane >> 3);
                s_hch2[pp ^ 1][k]      = pk2(h, hn);
                s_hch2[pp ^ 1][32 + k] = pk2(c, cn);
                s_hseq2[t][k ^ (t & 31)] = pk2(h, hn);
            }
        }
        __syncthreads();
    }
    {
        const int e2h = tid & 31;
        h2t du0[32], du1[32];
        {
            const f4t* p0 = (const f4t*)(dlu + (2 * e2h) * 64);
            const f4t* p1 = (const f4t*)(dlu + (2 * e2h + 1) * 64);
#pragma unroll
            for (int i = 0; i < 16; ++i) {
                f4t v0 = p0[i], v1 = p1[i];
                du0[2 * i] = pk2(v0.x, v0.y); du0[2 * i + 1] = pk2(v0.z, v0.w);
                du1[2 * i] = pk2(v1.x, v1.y); du1[2 * i + 1] = pk2(v1.z, v1.w);
            }
        }
        const float b0 = dlub[2 * e2h], b1 = dlub[2 * e2h + 1];
#pragma unroll 1
        for (int pass = 0; pass < 16; ++pass) {
            const int w = pass * 8 + (tid >> 5);
            float a0 = b0, a1 = b1;
            const int sww = w & 31;
#pragma unroll
            for (int i = 0; i < 32; ++i) {
                h2t hp = s_hseq2[w][i ^ sww];
                a0 = fdot2(hp, du0[i], a0);
                a1 = fdot2(hp, du1[i], a1);
            }
            s_pool[w * 32 + (e2h ^ (w & 31))] = pk2(a0 * CLOG, a1 * CLOG);
        }
    }
    __builtin_amdgcn_sched_barrier(0);

    const int tgt = tgtp[0];
    if (tid < 32) {
        s_wlvf[tid * 4 + 2] = dlv[2 * tid];
        s_wlvf[tid * 4 + 3] = dlv[2 * tid + 1];
    }
    if (tid < 64) s_hch2[0][tid] = pk2(0.f, 0.f);
    float dlvsum;
    { float v = dlv[tid & 63]; dlvsum = wsum(v); }
    h2t dlw_r[16];
    {
        const f2t* r = (const f2t*)(dlw + (tid >> 2) * 128 + (tid & 3) * 32);
#pragma unroll
        for (int i = 0; i < 16; ++i) { f2t v = r[i]; dlw_r[i] = pk2(v.x, v.y); }
    }
    const float dlwb_r = dlwb[tid >> 2];
    h2t dwhh_r[32];
    {
        const f2t* r = (const f2t*)(dWhh + jrow * 64);
#pragma unroll
        for (int i = 0; i < 32; ++i) { f2t v = r[i]; dwhh_r[i] = pk2(v.x, v.y); }
    }
    const float dwih_r  = dWih[jrow];
    const float dbsum_r = dbih[jrow] + dbhh[jrow];
    const float lp0     = dlp[0];
    const float lp1_r   = dlp[1 + (tid & 63)];
    const float lpb     = dlpb[0];
    c_reg = 0.f;
    float h_reg = 0.f;
    __syncthreads();

#pragma unroll 1
    for (int s = 0; s < WW - 1; ++s) {
        const int pp = s & 1;
        const float ys = xb[(size_t)tgt * WW + s];
        {
            const f4t* hc4 = (const f4t*)&s_hch2[pp][(tid & 3) * 16];
            float a = 0.f;
#pragma unroll
            for (int i = 0; i < 4; ++i) { f4t v = hc4[i]; DOT4(v, dlw_r, 4 * i, a); }
            a += __shfl_xor(a, 1, 64);
            a += __shfl_xor(a, 2, 64);
            float wo = (a + dlwb_r) * CLOG;
            float wn = __shfl_xor(wo, 4, 64);
            if (!(tid & 7)) { f2t st = {wo, wn}; *(f2t*)&s_wlvf[(tid >> 3) * 4] = st; }
        }
        __syncthreads();
        {
            const int w = tid >> 1, sw = w & 31;
            const h2t* udr = s_pool + w * 32;
            float a = 0.f;
#pragma unroll
            for (int j = 0; j < 16; ++j) {
                const int ep = (tid & 1) * 16 + j;
                f4t wl = s_wlv[ep];
                h2t u  = udr[ep ^ sw];
                float r0 = rcp_(ex2(wl.x + (float)u.x) + 1.f);
                float r1 = rcp_(ex2(wl.y + (float)u.y) + 1.f);
                a = fmaf(wl.z, r0, a);
                a = fmaf(wl.w, r1, a);
            }
            a += __shfl_xor(a, 1, 64);
            if (!(tid & 1)) s_soft[w] = ex2((dlvsum - 2.f * a) * L2E);
        }
        __syncthreads();
        float inv;
        {
            const int l = tid & 63;
            float sm = s_soft[l] + s_soft[64 + l];
            sm = wsum(sm);
            inv = rcp_(sm);
            const int e2 = tid & 31, pg = tid >> 5;
            float a0 = 0.f, a1 = 0.f;
#pragma unroll
            for (int j = 0; j < 16; ++j) {
                const int w = pg * 16 + j;
                float bw = s_soft[w];
                h2t hp = s_hseq2[w][e2 ^ (w & 31)];
                a0 = fmaf(bw, (float)hp.x, a0);
                a1 = fmaf(bw, (float)hp.y, a1);
            }
            a0 += __shfl_xor(a0, 32, 64);
            a1 += __shfl_xor(a1, 32, 64);
            if ((tid & 63) < 32) { f2t st = {a0, a1}; *(f2t*)&s_tmp[wq * 64 + e2 * 2] = st; }
        }
        __syncthreads();
        {
            const int l = tid & 63;
            float ctx = s_tmp[l] + s_tmp[64 + l] + s_tmp[128 + l] + s_tmp[192 + l];
            float term = ctx * inv * lp1_r;
            term = wsum(term);
            float yt = fmaf(ys, lp0, term + lpb);
            float gv = fmaf(yt, dwih_r, dbsum_r);
            const f4t* h4 = (const f4t*)&s_hch2[pp][0];
#pragma unroll
            for (int i = 0; i < 8; ++i) { f4t v = h4[i]; DOT4(v, dwhh_r, 4 * i, gv); }
            const int base = lane & ~3;
            float gi = __shfl(gv, base, 64);
            float gf = __shfl(gv, base + 1, 64);
            float g2 = __shfl(gv, base + 2, 64);
            float go = __shfl(gv, base + 3, 64);
            float c = sig_c(gf) * c_reg + sig_c(gi) * tanh_c(g2);
            float h = sig_c(go) * tanh_c(c);
            c_reg = c; h_reg = h;
            float hn = __shfl_xor(h, 4, 64);
            float cn = __shfl_xor(c, 4, 64);
            if (!(lane & 7)) {
                const int k = wq * 8 + (lane >> 3);
                s_hch2[pp ^ 1][k]      = pk2(h, hn);
                s_hch2[pp ^ 1][32 + k] = pk2(c, cn);
            }
        }
        __syncthreads();
    }
    {
        float term = 0.f;
        if (!(lane & 3)) term = h_reg * dly[uidx] + c_reg * dly[64 + uidx];
        term = wsum(term);
        if (lane == 0) s_tmp[wq] = term;
    }
    __syncthreads();
    if (tid == 0) out[b] = s_tmp[0] + s_tmp[1] + s_tmp[2] + s_tmp[3] + dlyb[0];
}

extern "C" void kernel_launch(void* const* d_in, const int* in_sizes, int n_in,
                              void* d_out, int out_size, void* d_ws, size_t ws_size,
                              hipStream_t stream) {
    (void)in_sizes; (void)n_in; (void)out_size;
    const float* x    = (const float*)d_in[0];
    const float* eWih = (const float*)d_in[1];
    const float* eWhh = (const float*)d_in[2];
    const float* ebih = (const float*)d_in[3];
    const float* ebhh = (const float*)d_in[4];
    const float* elv  = (const float*)d_in[5];
    const float* elw  = (const float*)d_in[6];
    const float* elwb = (const float*)d_in[7];
    const float* elu  = (const float*)d_in[8];
    const float* elub = (const float*)d_in[9];
    const float* dWih = (const float*)d_in[10];
    const float* dWhh = (const float*)d_in[11];
    const float* dbih = (const float*)d_in[12];
    const float* dbhh = (const float*)d_in[13];
    const float* dlv  = (const float*)d_in[14];
    const float* dlw  = (const float*)d_in[15];
    const float* dlwb = (const float*)d_in[16];
    const float* dlu  = (const float*)d_in[17];
    const float* dlub = (const float*)d_in[18];
    const float* dlp  = (const float*)d_in[19];
    const float* dlpb = (const float*)d_in[20];
    const float* dly  = (const float*)d_in[21];
    const float* dlyb = (const float*)d_in[22];
    const int*   tgt  = (const int*)d_in[23];
    float* out = (float*)d_out;

    const size_t need = (size_t)NB * WW * 32 * sizeof(h2t);  // 16 MiB
    if (d_ws && ws_size >= need) {
        darnn2_kernel<<<NB / 2, 256, 0, stream>>>(
            x, eWih, eWhh, ebih, ebhh, elv, elw, elwb, elu, elub,
            dWih, dWhh, dbih, dbhh, dlv, dlw, dlwb, dlu, dlub,
            dlp, dlpb, dly, dlyb, tgt, (h2t*)d_ws, out);
    } else {
        darnn1_kernel<<<NB, 256, 0, stream>>>(
            x, eWih, eWhh, ebih, ebhh, elv, elw, elwb, elu, elub,
            dWih, dWhh, dbih, dbhh, dlv, dlw, dlwb, dlu, dlub,
            dlp, dlpb, dly, dlyb, tgt, out);
    }
}

// Round 9
// 1647.146 us; speedup vs baseline: 1.2057x; 1.2057x over previous
//
#include <hip/hip_runtime.h>

#define NB 1024
#define NV 96
#define WW 128
#define EE 64
#define DD 64

typedef _Float16 h2t __attribute__((ext_vector_type(2)));
typedef float f2t __attribute__((ext_vector_type(2)));
typedef float f4t __attribute__((ext_vector_type(4)));

#define CLOG 2.885390081777927f   /* 2*log2(e) */
#define L2E  1.4426950408889634f  /* log2(e)   */

__device__ __forceinline__ float fdot2(h2t a, h2t b, float c) {
    return __builtin_amdgcn_fdot2(a, b, c, false);
}
__device__ __forceinline__ h2t pk2(float a, float b) {
    h2t r; r.x = (_Float16)a; r.y = (_Float16)b; return r;
}
__device__ __forceinline__ h2t bch(float f) { return __builtin_bit_cast(h2t, f); }
__device__ __forceinline__ float bcf(h2t p) { return __builtin_bit_cast(float, p); }
__device__ __forceinline__ float ex2(float x) { return __builtin_amdgcn_exp2f(x); }
__device__ __forceinline__ float rcp_(float x) { return __builtin_amdgcn_rcpf(x); }
__device__ __forceinline__ float sig_c(float x) { return rcp_(1.f + ex2(-x * L2E)); }
__device__ __forceinline__ float tanh_c(float x) { return 1.f - 2.f * rcp_(ex2(x * CLOG) + 1.f); }
__device__ __forceinline__ float wsum(float v) {
#pragma unroll
    for (int o = 32; o; o >>= 1) v += __shfl_xor(v, o, 64);
    return v;
}

#define DOT4(V, WR, B, ACC) do { \
    ACC = fdot2(bch((V).x), (WR)[(B) + 0], ACC); \
    ACC = fdot2(bch((V).y), (WR)[(B) + 1], ACC); \
    ACC = fdot2(bch((V).z), (WR)[(B) + 2], ACC); \
    ACC = fdot2(bch((V).w), (WR)[(B) + 3], ACC); } while (0)

#define DOT4W(V, W4, ACC) do { \
    ACC = fdot2(bch((V).x), bch((W4).x), ACC); \
    ACC = fdot2(bch((V).y), bch((W4).y), ACC); \
    ACC = fdot2(bch((V).z), bch((W4).z), ACC); \
    ACC = fdot2(bch((V).w), bch((W4).w), ACC); } while (0)

// ======================= 2-elements-per-block kernel =======================
__global__ __launch_bounds__(256, 2)
void darnn2_kernel(
    const float* __restrict__ x,
    const float* __restrict__ eWih, const float* __restrict__ eWhh,
    const float* __restrict__ ebih, const float* __restrict__ ebhh,
    const float* __restrict__ elv,  const float* __restrict__ elw,
    const float* __restrict__ elwb, const float* __restrict__ elu,
    const float* __restrict__ elub,
    const float* __restrict__ dWih, const float* __restrict__ dWhh,
    const float* __restrict__ dbih, const float* __restrict__ dbhh,
    const float* __restrict__ dlv,  const float* __restrict__ dlw,
    const float* __restrict__ dlwb, const float* __restrict__ dlu,
    const float* __restrict__ dlub, const float* __restrict__ dlp,
    const float* __restrict__ dlpb, const float* __restrict__ dly,
    const float* __restrict__ dlyb, const int* __restrict__ tgtp,
    h2t* __restrict__ hsg_all,
    float* __restrict__ out)
{
    // enc: s_pool2[wp*98 + n], wp<64, n<96 | dec: s_pool2[ep*131 + w], ep<32, w<128
    __shared__ __align__(16) f2t  s_pool2[64 * 98];      // 50176 B
    __shared__ __align__(16) f4t  s_wo4[64];
    __shared__ __align__(16) f2t  s_lv[64];
    __shared__ __align__(16) f2t  s_soft2[128];          // dec: wave-private regions
    __shared__ __align__(16) char s_u2v[2048];
    __shared__ __align__(16) h2t  s_hch2[2][2][64];
    __shared__ __align__(16) f4t  s_spw[4][256];
    __shared__ __align__(16) f4t  s_sph[2][256];
    __shared__ __align__(16) f2t  s_psum[4];
    __shared__ __align__(16) f2t  s_ytp[4];
    __shared__ float s_scal[8];

    h2t*  const s_xtA  = (h2t*)s_u2v;
    h2t*  const s_xtB  = (h2t*)(s_u2v + 1024);

    const int tid  = threadIdx.x;
    const int b    = blockIdx.x;
    const int lane = tid & 63, wq = tid >> 6;
    const int uidx = wq * 16 + (lane >> 2);
    const int jrow = (lane & 3) * 64 + uidx;
    const float* xbA = x + (size_t)(2 * b) * NV * WW;
    const float* xbB = xbA + NV * WW;
    h2t* hsgP = hsg_all + (size_t)b * (WW * 64);   // [w][32 k][2 el]

    float c_regA = 0.f, c_regB = 0.f;

    // ---------------- init ----------------
    if (tid < 64) {
        s_hch2[0][0][tid] = pk2(0.f, 0.f);
        s_hch2[0][1][tid] = pk2(0.f, 0.f);
        f2t lv = { elv[2 * tid], elv[2 * tid + 1] };
        s_lv[tid] = lv;
    }

    // ---------------- phase A: u_e (raw fp16, transposed) ----------------
    {
        const int o = tid >> 1, p = tid & 1;
        f4t lu4[16];
        const f4t* lur = (const f4t*)(elu + o * WW + p * 64);
#pragma unroll
        for (int i = 0; i < 16; ++i) lu4[i] = lur[i];
        const float lub_o = elub[o];
        for (int n = 0; n < NV; ++n) {
            const f4t* xrA = (const f4t*)(xbA + n * WW + p * 64);
            const f4t* xrB = (const f4t*)(xbB + n * WW + p * 64);
            float aA0 = 0.f, aA1 = 0.f, aB0 = 0.f, aB1 = 0.f;
#pragma unroll
            for (int i = 0; i < 8; ++i) {
                f4t vA = xrA[i], vB = xrB[i], l4 = lu4[i];
                f4t wA = xrA[8 + i], wB = xrB[8 + i], m4 = lu4[8 + i];
                aA0 = fmaf(vA.x, l4.x, aA0); aA0 = fmaf(vA.y, l4.y, aA0);
                aA0 = fmaf(vA.z, l4.z, aA0); aA0 = fmaf(vA.w, l4.w, aA0);
                aA1 = fmaf(wA.x, m4.x, aA1); aA1 = fmaf(wA.y, m4.y, aA1);
                aA1 = fmaf(wA.z, m4.z, aA1); aA1 = fmaf(wA.w, m4.w, aA1);
                aB0 = fmaf(vB.x, l4.x, aB0); aB0 = fmaf(vB.y, l4.y, aB0);
                aB0 = fmaf(vB.z, l4.z, aB0); aB0 = fmaf(vB.w, l4.w, aB0);
                aB1 = fmaf(wB.x, m4.x, aB1); aB1 = fmaf(wB.y, m4.y, aB1);
                aB1 = fmaf(wB.z, m4.z, aB1); aB1 = fmaf(wB.w, m4.w, aB1);
            }
            float aA = aA0 + aA1, aB = aB0 + aB1;
            aA += __shfl_xor(aA, 1, 64);
            aB += __shfl_xor(aB, 1, 64);
            float valA = aA + lub_o;
            float valB = aB + lub_o;
            float vnA = __shfl_xor(valA, 2, 64);
            float vnB = __shfl_xor(valB, 2, 64);
            if (!(tid & 3)) {
                const int op = tid >> 2;
                f2t st = { bcf(pk2(valA, vnA)), bcf(pk2(valB, vnB)) };
                s_pool2[op * 98 + n] = st;
            }
        }
    }
    __syncthreads();
    __builtin_amdgcn_sched_barrier(0);

    float elvsum;
    { f2t lv = s_lv[lane]; elvsum = wsum(lv.x + lv.y); }

    // ---------------- encoder weights ----------------
    h2t lw_r[32];
    {
        const f2t* r = (const f2t*)(elw + (tid >> 1) * 128 + (tid & 1) * 64);
#pragma unroll
        for (int i = 0; i < 32; ++i) { f2t v = r[i]; lw_r[i] = pk2(v.x, v.y); }
    }
    const float lwb_r = elwb[tid >> 1];
    h2t wih_r[32];
    {
        const f2t* r = (const f2t*)(eWih + jrow * 96);
#pragma unroll
        for (int i = 0; i < 32; ++i) { f2t v = r[i]; wih_r[i] = pk2(v.x, v.y); }
#pragma unroll
        for (int g = 0; g < 4; ++g) {
            f4t ws;
            { f2t v = r[32 + 4*g];     ws.x = bcf(pk2(v.x, v.y)); }
            { f2t v = r[33 + 4*g];     ws.y = bcf(pk2(v.x, v.y)); }
            { f2t v = r[34 + 4*g];     ws.z = bcf(pk2(v.x, v.y)); }
            { f2t v = r[35 + 4*g];     ws.w = bcf(pk2(v.x, v.y)); }
            s_spw[g][tid] = ws;
        }
    }
    h2t whh_r[24];
    {
        const f2t* r = (const f2t*)(eWhh + jrow * 64);
#pragma unroll
        for (int i = 0; i < 24; ++i) { f2t v = r[i]; whh_r[i] = pk2(v.x, v.y); }
#pragma unroll
        for (int g = 0; g < 2; ++g) {
            f4t ws;
            { f2t v = r[24 + 4*g];     ws.x = bcf(pk2(v.x, v.y)); }
            { f2t v = r[25 + 4*g];     ws.y = bcf(pk2(v.x, v.y)); }
            { f2t v = r[26 + 4*g];     ws.z = bcf(pk2(v.x, v.y)); }
            { f2t v = r[27 + 4*g];     ws.w = bcf(pk2(v.x, v.y)); }
            s_sph[g][tid] = ws;
        }
    }
    const float bsum_r = ebih[jrow] + ebhh[jrow];
    __builtin_amdgcn_sched_barrier(0);

    // ---------------- encoder recurrence: 3 barriers/step ----------------
#pragma unroll 1
    for (int t = 0; t < WW; ++t) {
        const int pp = t & 1;
        float xvA = 0.f, xvB = 0.f;
        if (!(tid & 1) && tid < 192) {
            const int n = tid >> 1;
            xvA = xbA[n * WW + t]; xvB = xbB[n * WW + t];
        }
        // ph1: w_out both elements (2 accums per element)
        {
            const f4t* hcA = (const f4t*)&s_hch2[pp][0][(tid & 1) * 32];
            const f4t* hcB = (const f4t*)&s_hch2[pp][1][(tid & 1) * 32];
            float aA0 = 0.f, aA1 = 0.f, aB0 = 0.f, aB1 = 0.f;
#pragma unroll
            for (int i = 0; i < 4; ++i) {
                f4t vA = hcA[i], vB = hcB[i];
                f4t wA = hcA[4 + i], wB = hcB[4 + i];
                DOT4(vA, lw_r, 4 * i, aA0);
                DOT4(wA, lw_r, 16 + 4 * i, aA1);
                DOT4(vB, lw_r, 4 * i, aB0);
                DOT4(wB, lw_r, 16 + 4 * i, aB1);
            }
            float aA = aA0 + aA1, aB = aB0 + aB1;
            aA += __shfl_xor(aA, 1, 64); aB += __shfl_xor(aB, 1, 64);
            float woA = (aA + lwb_r) * CLOG, woB = (aB + lwb_r) * CLOG;
            float wnA = __shfl_xor(woA, 2, 64), wnB = __shfl_xor(woB, 2, 64);
            if (!(tid & 3)) { f4t st = {woA, wnA, woB, wnB}; s_wo4[tid >> 2] = st; }
        }
        __syncthreads();
        // ph2: scores + exp (4 accums), unnormalized x_tilde, per-wave psum
        float prodA = 0.f, prodB = 0.f, eA = 0.f, eB = 0.f;
        if (tid < 192) {
            const int n = tid >> 1, part = tid & 1;
            const f4t* wor = s_wo4 + part * 32;
            const f2t* lvr = s_lv + part * 32;
            const f2t* uer = s_pool2 + part * 32 * 98 + n;
            float aA0 = 0.f, aA1 = 0.f, aB0 = 0.f, aB1 = 0.f;
#pragma unroll
            for (int j = 0; j < 16; ++j) {
                {
                    f4t w4 = wor[j];
                    f2t lv = lvr[j];
                    f2t up = uer[j * 98];
                    h2t uA = bch(up.x), uB = bch(up.y);
                    float g0A = fmaf((float)uA.x, CLOG, w4.x);
                    float g1A = fmaf((float)uA.y, CLOG, w4.y);
                    float g0B = fmaf((float)uB.x, CLOG, w4.z);
                    float g1B = fmaf((float)uB.y, CLOG, w4.w);
                    aA0 = fmaf(lv.x, rcp_(ex2(g0A) + 1.f), aA0);
                    aA0 = fmaf(lv.y, rcp_(ex2(g1A) + 1.f), aA0);
                    aB0 = fmaf(lv.x, rcp_(ex2(g0B) + 1.f), aB0);
                    aB0 = fmaf(lv.y, rcp_(ex2(g1B) + 1.f), aB0);
                }
                {
                    f4t w4 = wor[16 + j];
                    f2t lv = lvr[16 + j];
                    f2t up = uer[(16 + j) * 98];
                    h2t uA = bch(up.x), uB = bch(up.y);
                    float g0A = fmaf((float)uA.x, CLOG, w4.x);
                    float g1A = fmaf((float)uA.y, CLOG, w4.y);
                    float g0B = fmaf((float)uB.x, CLOG, w4.z);
                    float g1B = fmaf((float)uB.y, CLOG, w4.w);
                    aA1 = fmaf(lv.x, rcp_(ex2(g0A) + 1.f), aA1);
                    aA1 = fmaf(lv.y, rcp_(ex2(g1A) + 1.f), aA1);
                    aB1 = fmaf(lv.x, rcp_(ex2(g0B) + 1.f), aB1);
                    aB1 = fmaf(lv.y, rcp_(ex2(g1B) + 1.f), aB1);
                }
            }
            float aA = aA0 + aA1, aB = aB0 + aB1;
            aA += __shfl_xor(aA, 1, 64); aB += __shfl_xor(aB, 1, 64);
            if (!(tid & 1)) {
                eA = ex2((elvsum - 2.f * aA) * L2E);
                eB = ex2((elvsum - 2.f * aB) * L2E);
                prodA = eA * xvA; prodB = eB * xvB;
            }
        }
        {
            float p1A = __shfl_xor(prodA, 2, 64), p1B = __shfl_xor(prodB, 2, 64);
            if (tid < 192 && !(tid & 3)) {
                s_xtA[tid >> 2] = pk2(prodA, p1A);
                s_xtB[tid >> 2] = pk2(prodB, p1B);
            }
        }
        {
            float sA = eA, sB = eB;
#pragma unroll
            for (int o = 32; o; o >>= 1) { sA += __shfl_xor(sA, o, 64); sB += __shfl_xor(sB, o, 64); }
            if (lane == 0) { f2t st = {sA, sB}; s_psum[wq] = st; }
        }
        __syncthreads();
        // ph4: gates (2 accums per dot per element) + fused LSTM update
        {
            f2t q0 = s_psum[0], q1 = s_psum[1], q2 = s_psum[2], q3 = s_psum[3];
            const float invA = rcp_((q0.x + q1.x) + (q2.x + q3.x));
            const float invB = rcp_((q0.y + q1.y) + (q2.y + q3.y));
            float gxA0 = 0.f, gxA1 = 0.f, gxB0 = 0.f, gxB1 = 0.f;
            float ghA0 = bsum_r, ghA1 = 0.f, ghB0 = bsum_r, ghB1 = 0.f;
            const f4t* xtA4 = (const f4t*)s_xtA;
            const f4t* xtB4 = (const f4t*)s_xtB;
#pragma unroll
            for (int i = 0; i < 4; ++i) {
                f4t vA = xtA4[i], vB = xtB4[i];
                f4t wA = xtA4[4 + i], wB = xtB4[4 + i];
                DOT4(vA, wih_r, 4 * i, gxA0);
                DOT4(wA, wih_r, 16 + 4 * i, gxA1);
                DOT4(vB, wih_r, 4 * i, gxB0);
                DOT4(wB, wih_r, 16 + 4 * i, gxB1);
            }
#pragma unroll
            for (int g = 0; g < 2; ++g) {
                f4t w0 = s_spw[g][tid], w1 = s_spw[2 + g][tid];
                f4t vA = xtA4[8 + g], vB = xtB4[8 + g];
                f4t wA = xtA4[10 + g], wB = xtB4[10 + g];
                DOT4W(vA, w0, gxA0); DOT4W(wA, w1, gxA1);
                DOT4W(vB, w0, gxB0); DOT4W(wB, w1, gxB1);
            }
            const f4t* hA4 = (const f4t*)&s_hch2[pp][0][0];
            const f4t* hB4 = (const f4t*)&s_hch2[pp][1][0];
#pragma unroll
            for (int i = 0; i < 3; ++i) {
                f4t vA = hA4[i], vB = hB4[i];
                f4t wA = hA4[3 + i], wB = hB4[3 + i];
                DOT4(vA, whh_r, 4 * i, ghA0);
                DOT4(wA, whh_r, 12 + 4 * i, ghA1);
                DOT4(vB, whh_r, 4 * i, ghB0);
                DOT4(wB, whh_r, 12 + 4 * i, ghB1);
            }
            {
                f4t w0 = s_sph[0][tid], w1 = s_sph[1][tid];
                f4t vA = hA4[6], wA = hA4[7];
                f4t vB = hB4[6], wB = hB4[7];
                DOT4W(vA, w0, ghA0); DOT4W(wA, w1, ghA1);
                DOT4W(vB, w0, ghB0); DOT4W(wB, w1, ghB1);
            }
            float gA = fmaf(gxA0 + gxA1, invA, ghA0 + ghA1);
            float gB = fmaf(gxB0 + gxB1, invB, ghB0 + ghB1);
            const int base = lane & ~3;
            float giA = __shfl(gA, base, 64),     giB = __shfl(gB, base, 64);
            float gfA = __shfl(gA, base + 1, 64), gfB = __shfl(gB, base + 1, 64);
            float g2A = __shfl(gA, base + 2, 64), g2B = __shfl(gB, base + 2, 64);
            float goA = __shfl(gA, base + 3, 64), goB = __shfl(gB, base + 3, 64);
            float cA = sig_c(gfA) * c_regA + sig_c(giA) * tanh_c(g2A);
            float cB = sig_c(gfB) * c_regB + sig_c(giB) * tanh_c(g2B);
            float hA = sig_c(goA) * tanh_c(cA);
            float hB = sig_c(goB) * tanh_c(cB);
            c_regA = cA; c_regB = cB;
            float hnA = __shfl_xor(hA, 4, 64), cnA = __shfl_xor(cA, 4, 64);
            float hnB = __shfl_xor(hB, 4, 64), cnB = __shfl_xor(cB, 4, 64);
            if (!(lane & 7)) {
                const int k = wq * 8 + (lane >> 3);
                h2t phA = pk2(hA, hnA), phB = pk2(hB, hnB);
                s_hch2[pp ^ 1][0][k]      = phA;
                s_hch2[pp ^ 1][0][32 + k] = pk2(cA, cnA);
                s_hch2[pp ^ 1][1][k]      = phB;
                s_hch2[pp ^ 1][1][32 + k] = pk2(cB, cnB);
                f2t st = { bcf(phA), bcf(phB) };
                *(f2t*)&hsgP[t * 64 + k * 2] = st;
            }
        }
        __syncthreads();
    }

    // ---------------- u_d = h_seq @ dlu^T + dlub (raw, transposed, stride 131) ----
    {
        const int e2h = tid & 31;
        h2t du0[32], du1[32];
        {
            const f4t* p0 = (const f4t*)(dlu + (2 * e2h) * 64);
            const f4t* p1 = (const f4t*)(dlu + (2 * e2h + 1) * 64);
#pragma unroll
            for (int i = 0; i < 16; ++i) {
                f4t v0 = p0[i], v1 = p1[i];
                du0[2 * i] = pk2(v0.x, v0.y); du0[2 * i + 1] = pk2(v0.z, v0.w);
                du1[2 * i] = pk2(v1.x, v1.y); du1[2 * i + 1] = pk2(v1.z, v1.w);
            }
        }
        const float b0 = dlub[2 * e2h], b1 = dlub[2 * e2h + 1];
#pragma unroll 1
        for (int pass = 0; pass < 16; ++pass) {
            const int w = pass * 8 + (tid >> 5);
            float a0A = b0, a1A = b1, a0B = b0, a1B = b1;
            const f4t* hr = (const f4t*)(hsgP + w * 64);
#pragma unroll
            for (int i = 0; i < 16; ++i) {
                f4t v = hr[i];
                a0A = fdot2(bch(v.x), du0[2*i], a0A); a0A = fdot2(bch(v.z), du0[2*i+1], a0A);
                a1A = fdot2(bch(v.x), du1[2*i], a1A); a1A = fdot2(bch(v.z), du1[2*i+1], a1A);
                a0B = fdot2(bch(v.y), du0[2*i], a0B); a0B = fdot2(bch(v.w), du0[2*i+1], a0B);
                a1B = fdot2(bch(v.y), du1[2*i], a1B); a1B = fdot2(bch(v.w), du1[2*i+1], a1B);
            }
            f2t st = { bcf(pk2(a0A, a1A)), bcf(pk2(a0B, a1B)) };
            s_pool2[e2h * 131 + w] = st;
        }
    }
    __builtin_amdgcn_sched_barrier(0);

    // ---------------- decoder setup ----------------
    const int tgt = tgtp[0];
    if (tid < 32) { f2t lv = { dlv[2 * tid], dlv[2 * tid + 1] }; s_lv[tid] = lv; }
    if (tid < 64) {
        s_hch2[0][0][tid] = pk2(0.f, 0.f);
        s_hch2[0][1][tid] = pk2(0.f, 0.f);
    }
    float dlvsum;
    { float v = dlv[lane]; dlvsum = wsum(v); }
    h2t dlw_r[16];
    {
        const f2t* r = (const f2t*)(dlw + (tid >> 2) * 128 + (tid & 3) * 32);
#pragma unroll
        for (int i = 0; i < 16; ++i) { f2t v = r[i]; dlw_r[i] = pk2(v.x, v.y); }
    }
    const float dlwb_r = dlwb[tid >> 2];
    h2t dwhh_r[24];
    {
        const f2t* r = (const f2t*)(dWhh + jrow * 64);
#pragma unroll
        for (int i = 0; i < 24; ++i) { f2t v = r[i]; dwhh_r[i] = pk2(v.x, v.y); }
#pragma unroll
        for (int g = 0; g < 2; ++g) {
            f4t ws;
            { f2t v = r[24 + 4*g]; ws.x = bcf(pk2(v.x, v.y)); }
            { f2t v = r[25 + 4*g]; ws.y = bcf(pk2(v.x, v.y)); }
            { f2t v = r[26 + 4*g]; ws.z = bcf(pk2(v.x, v.y)); }
            { f2t v = r[27 + 4*g]; ws.w = bcf(pk2(v.x, v.y)); }
            s_sph[g][tid] = ws;
        }
    }
    const float dwih_r  = dWih[jrow];
    const float dbsum_r = dbih[jrow] + dbhh[jrow];
    const float lp0     = dlp[0];
    const h2t   lp1p    = pk2(dlp[1 + 2 * (tid & 31)], dlp[2 + 2 * (tid & 31)]);
    const float lpb     = dlpb[0];
    c_regA = 0.f; c_regB = 0.f;
    float h_regA = 0.f, h_regB = 0.f;
    __syncthreads();

    // ---------------- decoder recurrence: 3 barriers/step ----------------
#pragma unroll 1
    for (int s = 0; s < WW - 1; ++s) {
        const int pp = s & 1;
        const float ysA = xbA[(size_t)tgt * WW + s];
        const float ysB = xbB[(size_t)tgt * WW + s];
        // ph1': w_out_d (2 accums per element)
        {
            const f4t* hcA = (const f4t*)&s_hch2[pp][0][(tid & 3) * 16];
            const f4t* hcB = (const f4t*)&s_hch2[pp][1][(tid & 3) * 16];
            float aA0 = 0.f, aA1 = 0.f, aB0 = 0.f, aB1 = 0.f;
#pragma unroll
            for (int i = 0; i < 2; ++i) {
                f4t vA = hcA[i], vB = hcB[i];
                f4t wA = hcA[2 + i], wB = hcB[2 + i];
                DOT4(vA, dlw_r, 4 * i, aA0);
                DOT4(wA, dlw_r, 8 + 4 * i, aA1);
                DOT4(vB, dlw_r, 4 * i, aB0);
                DOT4(wB, dlw_r, 8 + 4 * i, aB1);
            }
            float aA = aA0 + aA1, aB = aB0 + aB1;
            aA += __shfl_xor(aA, 1, 64); aB += __shfl_xor(aB, 1, 64);
            aA += __shfl_xor(aA, 2, 64); aB += __shfl_xor(aB, 2, 64);
            float woA = (aA + dlwb_r) * CLOG, woB = (aB + dlwb_r) * CLOG;
            float wnA = __shfl_xor(woA, 4, 64), wnB = __shfl_xor(woB, 4, 64);
            if (!(tid & 7)) { f4t st = {woA, wnA, woB, wnB}; s_wo4[tid >> 3] = st; }
        }
        __syncthreads();
        // ph2'+ph3' merged: v scores + exp + per-wave psum, then context/ytp
        // partials using this wave's OWN soft values (same-wave LDS data is
        // visible after lgkmcnt — no barrier needed between score and context).
        {
            const int w = tid >> 1, part = tid & 1;
            const f4t* wor = s_wo4 + part * 16;
            const f2t* lvr = s_lv + part * 16;
            const f2t* udr = s_pool2 + w;
            const int rbase = part * 16;
            float aA0 = 0.f, aA1 = 0.f, aB0 = 0.f, aB1 = 0.f;
#pragma unroll
            for (int j = 0; j < 8; ++j) {
                {
                    f4t w4 = wor[j];
                    f2t lv = lvr[j];
                    f2t up = udr[(rbase + j) * 131];
                    h2t uA = bch(up.x), uB = bch(up.y);
                    float g0A = fmaf((float)uA.x, CLOG, w4.x);
                    float g1A = fmaf((float)uA.y, CLOG, w4.y);
                    float g0B = fmaf((float)uB.x, CLOG, w4.z);
                    float g1B = fmaf((float)uB.y, CLOG, w4.w);
                    aA0 = fmaf(lv.x, rcp_(ex2(g0A) + 1.f), aA0);
                    aA0 = fmaf(lv.y, rcp_(ex2(g1A) + 1.f), aA0);
                    aB0 = fmaf(lv.x, rcp_(ex2(g0B) + 1.f), aB0);
                    aB0 = fmaf(lv.y, rcp_(ex2(g1B) + 1.f), aB0);
                }
                {
                    f4t w4 = wor[8 + j];
                    f2t lv = lvr[8 + j];
                    f2t up = udr[(rbase + 8 + j) * 131];
                    h2t uA = bch(up.x), uB = bch(up.y);
                    float g0A = fmaf((float)uA.x, CLOG, w4.x);
                    float g1A = fmaf((float)uA.y, CLOG, w4.y);
                    float g0B = fmaf((float)uB.x, CLOG, w4.z);
                    float g1B = fmaf((float)uB.y, CLOG, w4.w);
                    aA1 = fmaf(lv.x, rcp_(ex2(g0A) + 1.f), aA1);
                    aA1 = fmaf(lv.y, rcp_(ex2(g1A) + 1.f), aA1);
                    aB1 = fmaf(lv.x, rcp_(ex2(g0B) + 1.f), aB1);
                    aB1 = fmaf(lv.y, rcp_(ex2(g1B) + 1.f), aB1);
                }
            }
            float aA = aA0 + aA1, aB = aB0 + aB1;
            aA += __shfl_xor(aA, 1, 64); aB += __shfl_xor(aB, 1, 64);
            float eA = 0.f, eB = 0.f;
            if (!(tid & 1)) {
                eA = ex2((dlvsum - 2.f * aA) * L2E);
                eB = ex2((dlvsum - 2.f * aB) * L2E);
                f2t st = {eA, eB}; s_soft2[w] = st;
            }
            float sA = eA, sB = eB;
#pragma unroll
            for (int o = 32; o; o >>= 1) { sA += __shfl_xor(sA, o, 64); sB += __shfl_xor(sB, o, 64); }
            if (lane == 0) { f2t st = {sA, sB}; s_psum[wq] = st; }

            // context/y_tilde partials over this wave's own 32 w's.
            // lane<32: w in [wq*32, wq*32+16); lane>=32: w in [wq*32+16, wq*32+32).
            const int e2 = lane & 31;
            const int wb = wq * 32 + ((lane >> 5) << 4);
            float ytA0 = 0.f, ytA1 = 0.f, ytB0 = 0.f, ytB1 = 0.f;
#pragma unroll
            for (int j = 0; j < 8; ++j) {
                const int w0 = wb + j, w1 = wb + 8 + j;
                f2t be0 = s_soft2[w0], be1 = s_soft2[w1];
                f2t hp0 = *(const f2t*)&hsgP[w0 * 64 + e2 * 2];
                f2t hp1 = *(const f2t*)&hsgP[w1 * 64 + e2 * 2];
                ytA0 = fmaf(be0.x, fdot2(bch(hp0.x), lp1p, 0.f), ytA0);
                ytA1 = fmaf(be1.x, fdot2(bch(hp1.x), lp1p, 0.f), ytA1);
                ytB0 = fmaf(be0.y, fdot2(bch(hp0.y), lp1p, 0.f), ytB0);
                ytB1 = fmaf(be1.y, fdot2(bch(hp1.y), lp1p, 0.f), ytB1);
            }
            float ytA = ytA0 + ytA1, ytB = ytB0 + ytB1;
#pragma unroll
            for (int o = 32; o; o >>= 1) { ytA += __shfl_xor(ytA, o, 64); ytB += __shfl_xor(ytB, o, 64); }
            if (lane == 0) { f2t st = {ytA, ytB}; s_ytp[wq] = st; }
        }
        __syncthreads();
        // ph4': y_tilde + gates (2 accums) + update
        {
            f2t q0 = s_psum[0], q1 = s_psum[1], q2 = s_psum[2], q3 = s_psum[3];
            f2t y0 = s_ytp[0],  y1 = s_ytp[1],  y2 = s_ytp[2],  y3 = s_ytp[3];
            const float invA = rcp_((q0.x + q1.x) + (q2.x + q3.x));
            const float invB = rcp_((q0.y + q1.y) + (q2.y + q3.y));
            float ytA = fmaf(ysA, lp0, ((y0.x + y1.x) + (y2.x + y3.x)) * invA + lpb);
            float ytB = fmaf(ysB, lp0, ((y0.y + y1.y) + (y2.y + y3.y)) * invB + lpb);
            float gA0 = fmaf(ytA, dwih_r, dbsum_r), gA1 = 0.f;
            float gB0 = fmaf(ytB, dwih_r, dbsum_r), gB1 = 0.f;
            const f4t* hA4 = (const f4t*)&s_hch2[pp][0][0];
            const f4t* hB4 = (const f4t*)&s_hch2[pp][1][0];
#pragma unroll
            for (int i = 0; i < 3; ++i) {
                f4t vA = hA4[i], vB = hB4[i];
                f4t wA = hA4[3 + i], wB = hB4[3 + i];
                DOT4(vA, dwhh_r, 4 * i, gA0);
                DOT4(wA, dwhh_r, 12 + 4 * i, gA1);
                DOT4(vB, dwhh_r, 4 * i, gB0);
                DOT4(wB, dwhh_r, 12 + 4 * i, gB1);
            }
            {
                f4t w0 = s_sph[0][tid], w1 = s_sph[1][tid];
                f4t vA = hA4[6], wA = hA4[7];
                f4t vB = hB4[6], wB = hB4[7];
                DOT4W(vA, w0, gA0); DOT4W(wA, w1, gA1);
                DOT4W(vB, w0, gB0); DOT4W(wB, w1, gB1);
            }
            float gA = gA0 + gA1, gB = gB0 + gB1;
            const int base = lane & ~3;
            float giA = __shfl(gA, base, 64),     giB = __shfl(gB, base, 64);
            float gfA = __shfl(gA, base + 1, 64), gfB = __shfl(gB, base + 1, 64);
            float g2A = __shfl(gA, base + 2, 64), g2B = __shfl(gB, base + 2, 64);
            float goA = __shfl(gA, base + 3, 64), goB = __shfl(gB, base + 3, 64);
            float cA = sig_c(gfA) * c_regA + sig_c(giA) * tanh_c(g2A);
            float cB = sig_c(gfB) * c_regB + sig_c(giB) * tanh_c(g2B);
            float hA = sig_c(goA) * tanh_c(cA);
            float hB = sig_c(goB) * tanh_c(cB);
            c_regA = cA; c_regB = cB; h_regA = hA; h_regB = hB;
            float hnA = __shfl_xor(hA, 4, 64), cnA = __shfl_xor(cA, 4, 64);
            float hnB = __shfl_xor(hB, 4, 64), cnB = __shfl_xor(cB, 4, 64);
            if (!(lane & 7)) {
                const int k = wq * 8 + (lane >> 3);
                s_hch2[pp ^ 1][0][k]      = pk2(hA, hnA);
                s_hch2[pp ^ 1][0][32 + k] = pk2(cA, cnA);
                s_hch2[pp ^ 1][1][k]      = pk2(hB, hnB);
                s_hch2[pp ^ 1][1][32 + k] = pk2(cB, cnB);
            }
        }
        __syncthreads();
    }

    // ---------------- output ----------------
    {
        float termA = 0.f, termB = 0.f;
        if (!(lane & 3)) {
            termA = h_regA * dly[uidx] + c_regA * dly[64 + uidx];
            termB = h_regB * dly[uidx] + c_regB * dly[64 + uidx];
        }
#pragma unroll
        for (int o = 32; o; o >>= 1) {
            termA += __shfl_xor(termA, o, 64);
            termB += __shfl_xor(termB, o, 64);
        }
        if (lane == 0) { s_scal[wq] = termA; s_scal[4 + wq] = termB; }
    }
    __syncthreads();
    if (tid == 0) out[2 * b]     = s_scal[0] + s_scal[1] + s_scal[2] + s_scal[3] + dlyb[0];
    if (tid == 1) out[2 * b + 1] = s_scal[4] + s_scal[5] + s_scal[6] + s_scal[7] + dlyb[0];
}

// ======================= fallback: 1-element kernel (LDS h_seq) ========
__global__ __launch_bounds__(256, 2)
void darnn1_kernel(
    const float* __restrict__ x,
    const float* __restrict__ eWih, const float* __restrict__ eWhh,
    const float* __restrict__ ebih, const float* __restrict__ ebhh,
    const float* __restrict__ elv,  const float* __restrict__ elw,
    const float* __restrict__ elwb, const float* __restrict__ elu,
    const float* __restrict__ elub,
    const float* __restrict__ dWih, const float* __restrict__ dWhh,
    const float* __restrict__ dbih, const float* __restrict__ dbhh,
    const float* __restrict__ dlv,  const float* __restrict__ dlw,
    const float* __restrict__ dlwb, const float* __restrict__ dlu,
    const float* __restrict__ dlub, const float* __restrict__ dlp,
    const float* __restrict__ dlpb, const float* __restrict__ dly,
    const float* __restrict__ dlyb, const int* __restrict__ tgtp,
    float* __restrict__ out)
{
    __shared__ __align__(16) h2t  s_pool[96 * 64];
    __shared__ __align__(16) h2t  s_hseq2[WW][32];
    __shared__ __align__(16) f4t  s_wlv[64];
    __shared__ __align__(16) char s_u2[1024];
    __shared__ __align__(16) float s_soft[128];
    __shared__ __align__(16) h2t  s_hch2[2][64];
    __shared__ __align__(16) f4t  s_spillh[2][256];
    __shared__ __align__(16) f4t  s_spillw[256];

    float* s_wlvf = (float*)s_wlv;
    h2t*  const s_xt  = (h2t*)s_u2;
    float* const s_tmp = (float*)s_u2;

    const int tid  = threadIdx.x;
    const int b    = blockIdx.x;
    const int lane = tid & 63, wq = tid >> 6;
    const int uidx = wq * 16 + (lane >> 2);
    const int jrow = (lane & 3) * 64 + uidx;
    const float* xb = x + (size_t)b * NV * WW;

    float c_reg = 0.f;

    if (tid >= 96 && tid < 128) s_soft[tid] = 0.f;
    if (tid < 64) {
        s_hch2[0][tid] = pk2(0.f, 0.f);
        s_wlvf[tid * 4 + 2] = elv[2 * tid];
        s_wlvf[tid * 4 + 3] = elv[2 * tid + 1];
    }
    {
        const int o = tid >> 1, p = tid & 1;
        f4t lu4[16];
        const f4t* lur = (const f4t*)(elu + o * WW + p * 64);
#pragma unroll
        for (int i = 0; i < 16; ++i) lu4[i] = lur[i];
        const float lub_o = elub[o];
        for (int n = 0; n < NV; ++n) {
            const f4t* xr = (const f4t*)(xb + n * WW + p * 64);
            float a = 0.f;
#pragma unroll
            for (int i = 0; i < 16; ++i) {
                f4t v = xr[i], l4 = lu4[i];
                a = fmaf(v.x, l4.x, a); a = fmaf(v.y, l4.y, a);
                a = fmaf(v.z, l4.z, a); a = fmaf(v.w, l4.w, a);
            }
            a += __shfl_xor(a, 1, 64);
            float val = (a + lub_o) * CLOG;
            float vn  = __shfl_xor(val, 2, 64);
            if (!(tid & 3)) s_pool[n * 64 + ((tid >> 2) ^ (n & 31))] = pk2(val, vn);
        }
    }
    __syncthreads();
    __builtin_amdgcn_sched_barrier(0);

    float elvsum;
    {
        const f2t lvp = *(const f2t*)&s_wlvf[(tid & 63) * 4 + 2];
        elvsum = wsum(lvp.x + lvp.y);
    }
    h2t lw_r[32];
    {
        const f2t* r = (const f2t*)(elw + (tid >> 1) * 128 + (tid & 1) * 64);
#pragma unroll
        for (int i = 0; i < 32; ++i) { f2t v = r[i]; lw_r[i] = pk2(v.x, v.y); }
    }
    const float lwb_r = elwb[tid >> 1];
    h2t wih_r[44];
    {
        const f2t* r = (const f2t*)(eWih + jrow * 96);
#pragma unroll
        for (int i = 0; i < 44; ++i) { f2t v = r[i]; wih_r[i] = pk2(v.x, v.y); }
        f4t ws;
        { f2t v = r[44]; ws.x = bcf(pk2(v.x, v.y)); }
        { f2t v = r[45]; ws.y = bcf(pk2(v.x, v.y)); }
        { f2t v = r[46]; ws.z = bcf(pk2(v.x, v.y)); }
        { f2t v = r[47]; ws.w = bcf(pk2(v.x, v.y)); }
        s_spillw[tid] = ws;
    }
    h2t whh_r[24];
    {
        const f2t* r = (const f2t*)(eWhh + jrow * 64);
#pragma unroll
        for (int i = 0; i < 24; ++i) { f2t v = r[i]; whh_r[i] = pk2(v.x, v.y); }
        f4t w0, w1;
        { f2t v = r[24]; w0.x = bcf(pk2(v.x, v.y)); }
        { f2t v = r[25]; w0.y = bcf(pk2(v.x, v.y)); }
        { f2t v = r[26]; w0.z = bcf(pk2(v.x, v.y)); }
        { f2t v = r[27]; w0.w = bcf(pk2(v.x, v.y)); }
        { f2t v = r[28]; w1.x = bcf(pk2(v.x, v.y)); }
        { f2t v = r[29]; w1.y = bcf(pk2(v.x, v.y)); }
        { f2t v = r[30]; w1.z = bcf(pk2(v.x, v.y)); }
        { f2t v = r[31]; w1.w = bcf(pk2(v.x, v.y)); }
        s_spillh[0][tid] = w0;
        s_spillh[1][tid] = w1;
    }
    const float bsum_r = ebih[jrow] + ebhh[jrow];
    __builtin_amdgcn_sched_barrier(0);

#pragma unroll 1
    for (int t = 0; t < WW; ++t) {
        const int pp = t & 1;
        float xv = 0.f;
        if (!(tid & 1) && tid < 192) xv = xb[(tid >> 1) * WW + t];
        {
            const f4t* hc4 = (const f4t*)&s_hch2[pp][(tid & 1) * 32];
            float a = 0.f;
#pragma unroll
            for (int i = 0; i < 8; ++i) { f4t v = hc4[i]; DOT4(v, lw_r, 4 * i, a); }
            a += __shfl_xor(a, 1, 64);
            float wo = (a + lwb_r) * CLOG;
            float wn = __shfl_xor(wo, 2, 64);
            if (!(tid & 3)) { f2t st = {wo, wn}; *(f2t*)&s_wlvf[(tid >> 2) * 4] = st; }
        }
        __syncthreads();
        float prod = 0.f;
        if (tid < 192) {
            const int n = tid >> 1, sw = n & 31;
            const h2t* uer = s_pool + n * 64;
            float a = 0.f;
#pragma unroll
            for (int j = 0; j < 32; ++j) {
                const int wp = (tid & 1) * 32 + j;
                f4t wl = s_wlv[wp];
                h2t u  = uer[wp ^ sw];
                float r0 = rcp_(ex2(wl.x + (float)u.x) + 1.f);
                float r1 = rcp_(ex2(wl.y + (float)u.y) + 1.f);
                a = fmaf(wl.z, r0, a);
                a = fmaf(wl.w, r1, a);
            }
            a += __shfl_xor(a, 1, 64);
            if (!(tid & 1)) {
                float e = ex2((elvsum - 2.f * a) * L2E);
                prod = e * xv;
                s_soft[tid >> 1] = e;
            }
        }
        __syncthreads();
        if (tid < 192) {
            const int l = tid & 63;
            float sm = s_soft[l] + s_soft[64 + l];
            sm = wsum(sm);
            float inv = rcp_(sm);
            float p1 = __shfl_xor(prod, 2, 64);
            if (!(tid & 3)) s_xt[tid >> 2] = pk2(prod * inv, p1 * inv);
        }
        __syncthreads();
        {
            float gv = bsum_r;
            const f4t* xt4 = (const f4t*)s_xt;
#pragma unroll
            for (int i = 0; i < 11; ++i) { f4t v = xt4[i]; DOT4(v, wih_r, 4 * i, gv); }
            { f4t v = xt4[11]; f4t w = s_spillw[tid]; DOT4W(v, w, gv); }
            const f4t* h4 = (const f4t*)&s_hch2[pp][0];
#pragma unroll
            for (int i = 0; i < 6; ++i) { f4t v = h4[i]; DOT4(v, whh_r, 4 * i, gv); }
            { f4t v = h4[6]; f4t w = s_spillh[0][tid]; DOT4W(v, w, gv); }
            { f4t v = h4[7]; f4t w = s_spillh[1][tid]; DOT4W(v, w, gv); }
            const int base = lane & ~3;
            float gi = __shfl(gv, base, 64);
            float gf = __shfl(gv, base + 1, 64);
            float g2 = __shfl(gv, base + 2, 64);
            float go = __shfl(gv, base + 3, 64);
            float c = sig_c(gf) * c_reg + sig_c(gi) * tanh_c(g2);
            float h = sig_c(go) * tanh_c(c);
            c_reg = c;
            float hn = __shfl_xor(h, 4, 64);
            float cn = __shfl_xor(c, 4, 64);
            if (!(lane & 7)) {
                const int k = wq * 8 + (lane >> 3);
                s_hch2[pp ^ 1][k]      = pk2(h, hn);
                s_hch2[pp ^ 1][32 + k] = pk2(c, cn);
                s_hseq2[t][k ^ (t & 31)] = pk2(h, hn);
            }
        }
        __syncthreads();
    }
    {
        const int e2h = tid & 31;
        h2t du0[32], du1[32];
        {
            const f4t* p0 = (const f4t*)(dlu + (2 * e2h) * 64);
            const f4t* p1 = (const f4t*)(dlu + (2 * e2h + 1) * 64);
#pragma unroll
            for (int i = 0; i < 16; ++i) {
                f4t v0 = p0[i], v1 = p1[i];
                du0[2 * i] = pk2(v0.x, v0.y); du0[2 * i + 1] = pk2(v0.z, v0.w);
                du1[2 * i] = pk2(v1.x, v1.y); du1[2 * i + 1] = pk2(v1.z, v1.w);
            }
        }
        const float b0 = dlub[2 * e2h], b1 = dlub[2 * e2h + 1];
#pragma unroll 1
        for (int pass = 0; pass < 16; ++pass) {
            const int w = pass * 8 + (tid >> 5);
            float a0 = b0, a1 = b1;
            const int sww = w & 31;
#pragma unroll
            for (int i = 0; i < 32; ++i) {
                h2t hp = s_hseq2[w][i ^ sww];
                a0 = fdot2(hp, du0[i], a0);
                a1 = fdot2(hp, du1[i], a1);
            }
            s_pool[w * 32 + (e2h ^ (w & 31))] = pk2(a0 * CLOG, a1 * CLOG);
        }
    }
    __builtin_amdgcn_sched_barrier(0);

    const int tgt = tgtp[0];
    if (tid < 32) {
        s_wlvf[tid * 4 + 2] = dlv[2 * tid];
        s_wlvf[tid * 4 + 3] = dlv[2 * tid + 1];
    }
    if (tid < 64) s_hch2[0][tid] = pk2(0.f, 0.f);
    float dlvsum;
    { float v = dlv[tid & 63]; dlvsum = wsum(v); }
    h2t dlw_r[16];
    {
        const f2t* r = (const f2t*)(dlw + (tid >> 2) * 128 + (tid & 3) * 32);
#pragma unroll
        for (int i = 0; i < 16; ++i) { f2t v = r[i]; dlw_r[i] = pk2(v.x, v.y); }
    }
    const float dlwb_r = dlwb[tid >> 2];
    h2t dwhh_r[32];
    {
        const f2t* r = (const f2t*)(dWhh + jrow * 64);
#pragma unroll
        for (int i = 0; i < 32; ++i) { f2t v = r[i]; dwhh_r[i] = pk2(v.x, v.y); }
    }
    const float dwih_r  = dWih[jrow];
    const float dbsum_r = dbih[jrow] + dbhh[jrow];
    const float lp0     = dlp[0];
    const float lp1_r   = dlp[1 + (tid & 63)];
    const float lpb     = dlpb[0];
    c_reg = 0.f;
    float h_reg = 0.f;
    __syncthreads();

#pragma unroll 1
    for (int s = 0; s < WW - 1; ++s) {
        const int pp = s & 1;
        const float ys = xb[(size_t)tgt * WW + s];
        {
            const f4t* hc4 = (const f4t*)&s_hch2[pp][(tid & 3) * 16];
            float a = 0.f;
#pragma unroll
            for (int i = 0; i < 4; ++i) { f4t v = hc4[i]; DOT4(v, dlw_r, 4 * i, a); }
            a += __shfl_xor(a, 1, 64);
            a += __shfl_xor(a, 2, 64);
            float wo = (a + dlwb_r) * CLOG;
            float wn = __shfl_xor(wo, 4, 64);
            if (!(tid & 7)) { f2t st = {wo, wn}; *(f2t*)&s_wlvf[(tid >> 3) * 4] = st; }
        }
        __syncthreads();
        {
            const int w = tid >> 1, sw = w & 31;
            const h2t* udr = s_pool + w * 32;
            float a = 0.f;
#pragma unroll
            for (int j = 0; j < 16; ++j) {
                const int ep = (tid & 1) * 16 + j;
                f4t wl = s_wlv[ep];
                h2t u  = udr[ep ^ sw];
                float r0 = rcp_(ex2(wl.x + (float)u.x) + 1.f);
                float r1 = rcp_(ex2(wl.y + (float)u.y) + 1.f);
                a = fmaf(wl.z, r0, a);
                a = fmaf(wl.w, r1, a);
            }
            a += __shfl_xor(a, 1, 64);
            if (!(tid & 1)) s_soft[w] = ex2((dlvsum - 2.f * a) * L2E);
        }
        __syncthreads();
        float inv;
        {
            const int l = tid & 63;
            float sm = s_soft[l] + s_soft[64 + l];
            sm = wsum(sm);
            inv = rcp_(sm);
            const int e2 = tid & 31, pg = tid >> 5;
            float a0 = 0.f, a1 = 0.f;
#pragma unroll
            for (int j = 0; j < 16; ++j) {
                const int w = pg * 16 + j;
                float bw = s_soft[w];
                h2t hp = s_hseq2[w][e2 ^ (w & 31)];
                a0 = fmaf(bw, (float)hp.x, a0);
                a1 = fmaf(bw, (float)hp.y, a1);
            }
            a0 += __shfl_xor(a0, 32, 64);
            a1 += __shfl_xor(a1, 32, 64);
            if ((tid & 63) < 32) { f2t st = {a0, a1}; *(f2t*)&s_tmp[wq * 64 + e2 * 2] = st; }
        }
        __syncthreads();
        {
            const int l = tid & 63;
            float ctx = s_tmp[l] + s_tmp[64 + l] + s_tmp[128 + l] + s_tmp[192 + l];
            float term = ctx * inv * lp1_r;
            term = wsum(term);
            float yt = fmaf(ys, lp0, term + lpb);
            float gv = fmaf(yt, dwih_r, dbsum_r);
            const f4t* h4 = (const f4t*)&s_hch2[pp][0];
#pragma unroll
            for (int i = 0; i < 8; ++i) { f4t v = h4[i]; DOT4(v, dwhh_r, 4 * i, gv); }
            const int base = lane & ~3;
            float gi = __shfl(gv, base, 64);
            float gf = __shfl(gv, base + 1, 64);
            float g2 = __shfl(gv, base + 2, 64);
            float go = __shfl(gv, base + 3, 64);
            float c = sig_c(gf) * c_reg + sig_c(gi) * tanh_c(g2);
            float h = sig_c(go) * tanh_c(c);
            c_reg = c; h_reg = h;
            float hn = __shfl_xor(h, 4, 64);
            float cn = __shfl_xor(c, 4, 64);
            if (!(lane & 7)) {
                const int k = wq * 8 + (lane >> 3);
                s_hch2[pp ^ 1][k]      = pk2(h, hn);
                s_hch2[pp ^ 1][32 + k] = pk2(c, cn);
            }
        }
        __syncthreads();
    }
    {
        float term = 0.f;
        if (!(lane & 3)) term = h_reg * dly[uidx] + c_reg * dly[64 + uidx];
        term = wsum(term);
        if (lane == 0) s_tmp[wq] = term;
    }
    __syncthreads();
    if (tid == 0) out[b] = s_tmp[0] + s_tmp[1] + s_tmp[2] + s_tmp[3] + dlyb[0];
}

extern "C" void kernel_launch(void* const* d_in, const int* in_sizes, int n_in,
                              void* d_out, int out_size, void* d_ws, size_t ws_size,
                              hipStream_t stream) {
    (void)in_sizes; (void)n_in; (void)out_size;
    const float* x    = (const float*)d_in[0];
    const float* eWih = (const float*)d_in[1];
    const float* eWhh = (const float*)d_in[2];
    const float* ebih = (const float*)d_in[3];
    const float* ebhh = (const float*)d_in[4];
    const float* elv  = (const float*)d_in[5];
    const float* elw  = (const float*)d_in[6];
    const float* elwb = (const float*)d_in[7];
    const float* elu  = (const float*)d_in[8];
    const float* elub = (const float*)d_in[9];
    const float* dWih = (const float*)d_in[10];
    const float* dWhh = (const float*)d_in[11];
    const float* dbih = (const float*)d_in[12];
    const float* dbhh = (const float*)d_in[13];
    const float* dlv  = (const float*)d_in[14];
    const float* dlw  = (const float*)d_in[15];
    const float* dlwb = (const float*)d_in[16];
    const float* dlu  = (const float*)d_in[17];
    const float* dlub = (const float*)d_in[18];
    const float* dlp  = (const float*)d_in[19];
    const float* dlpb = (const float*)d_in[20];
    const float* dly  = (const float*)d_in[21];
    const float* dlyb = (const float*)d_in[22];
    const int*   tgt  = (const int*)d_in[23];
    float* out = (float*)d_out;

    const size_t need = (size_t)NB * WW * 32 * sizeof(h2t);  // 16 MiB
    if (d_ws && ws_size >= need) {
        darnn2_kernel<<<NB / 2, 256, 0, stream>>>(
            x, eWih, eWhh, ebih, ebhh, elv, elw, elwb, elu, elub,
            dWih, dWhh, dbih, dbhh, dlv, dlw, dlwb, dlu, dlub,
            dlp, dlpb, dly, dlyb, tgt, (h2t*)d_ws, out);
    } else {
        darnn1_kernel<<<NB, 256, 0, stream>>>(
            x, eWih, eWhh, ebih, ebhh, elv, elw, elwb, elu, elub,
            dWih, dWhh, dbih, dbhh, dlv, dlw, dlwb, dlu, dlub,
            dlp, dlpb, dly, dlyb, tgt, out);
    }
}